// Round 2
// baseline (1341.616 us; speedup 1.0000x reference)
//
#include <hip/hip_runtime.h>
#include <stdint.h>

#define DEVI __device__ __forceinline__

typedef __attribute__((ext_vector_type(8))) short bf16x8;
typedef __attribute__((ext_vector_type(4))) float f32x4;
typedef __attribute__((ext_vector_type(4))) unsigned short us4;
typedef unsigned short u16;

constexpr int B_ = 4, S_ = 5, H_ = 4, C_ = 1024, D_ = 256;
constexpr int LQ = 4096, LK = 400, LKP = 448, LKM = 512;

DEVI u16 f2b(float f){
  uint32_t x = __float_as_uint(f);
  uint32_t r = (x + 0x7FFFu + ((x >> 16) & 1u)) >> 16;
  return (u16)r;
}

typedef __attribute__((address_space(1))) const void ASG;
typedef __attribute__((address_space(3))) void ASL;
DEVI void gload16(const void* g, void* l){
  __builtin_amdgcn_global_load_lds((ASG*)g, (ASL*)l, 16, 0, 0);
}

// ---------------- fp32 -> bf16 convert ----------------
__global__ __launch_bounds__(256) void k_cvt(const float* __restrict__ s, u16* __restrict__ d, int n4){
  int i = blockIdx.x*256 + threadIdx.x;
  if (i >= n4) return;
  float4 v = ((const float4*)s)[i];
  us4 o; o.x = f2b(v.x); o.y = f2b(v.y); o.z = f2b(v.z); o.w = f2b(v.w);
  *(us4*)(d + (size_t)i*4) = o;
}

// ---------------- base_feat [B][C][LQ] -> Xb bf16 [B][LQ][C] ----------------
__global__ __launch_bounds__(256) void k_transpose_x(const float* __restrict__ base, u16* __restrict__ Xb){
  __shared__ float t[32][33];
  int l0 = blockIdx.x*32, c0 = blockIdx.y*32, b = blockIdx.z;
  int tx = threadIdx.x & 31, ty = threadIdx.x >> 5;
  const float* src = base + ((size_t)b*C_ + c0)*LQ + l0;
  #pragma unroll
  for (int i=0;i<4;i++){ int cc = ty + i*8; t[cc][tx] = src[(size_t)cc*LQ + tx]; }
  __syncthreads();
  u16* dst = Xb + ((size_t)b*LQ + l0)*C_ + c0;
  #pragma unroll
  for (int i=0;i<4;i++){ int ll = ty + i*8; dst[(size_t)ll*C_ + tx] = f2b(t[tx][ll]); }
}

// ---------------- support + pe -> smat_kc [S][B][512][C] (rows 400..511 zero) ----------------
__global__ __launch_bounds__(256) void k_build_smat(const float* __restrict__ sup, u16* __restrict__ kc){
  __shared__ float t[32][33];
  int p0 = blockIdx.x*32, c0 = blockIdx.y*32;
  int s = blockIdx.z / B_, b = blockIdx.z % B_;
  int tx = threadIdx.x & 31, ty = threadIdx.x >> 5;
  const float* src = sup + ((size_t)(b*S_ + s)*C_ + c0)*LK + p0;
  #pragma unroll
  for (int i=0;i<4;i++){
    int cc = ty + i*8;
    int p = p0 + tx;
    int c = c0 + cc;
    float v = 0.f;
    if (p < LK){
      v = src[(size_t)cc*LK + tx];
      float dv = expf(-(float)(c & ~1) * (9.210340371976184f / 1024.f));
      float arg = (float)p * dv;
      v += (c & 1) ? cosf(arg) : sinf(arg);
    }
    t[cc][tx] = v;
  }
  __syncthreads();
  u16* dkc = kc + ((size_t)((s*B_ + b)*LKM + p0))*C_ + c0;
  #pragma unroll
  for (int i=0;i<4;i++){ int pp = ty + i*8; dkc[(size_t)pp*C_ + tx] = f2b(t[tx][pp]); }
}

// ---------------- generic bf16 MFMA GEMM: C[M][N] = A[M][K] * B[N][K]^T ----------------
// 128x128 tile, 4 waves (2x2 of 64x64), BK=64, global_load_lds with pre-swizzled source.
// CMODE 0: bf16 row-major store C[m*ldc+n]. CMODE 1: fp32 transposed store C[n*ldc+m] (+=acc if ACC).
template<int CMODE, bool ACC, bool BIAS>
__global__ __launch_bounds__(256) void k_gemm(
    const u16* __restrict__ A, const u16* __restrict__ Bm, void* __restrict__ Cm,
    const float* __restrict__ bias,
    int tilesM, int lda, int ldb, int ldc, int Kc,
    int bdiv, int64_t aS0, int64_t aS1, int64_t bS0, int64_t bS1,
    int64_t cS0, int64_t cS1, int biasS0, float scale, int Nmax){
  __shared__ __align__(16) u16 lA[128*64];
  __shared__ __align__(16) u16 lB[128*64];
  int tid = threadIdx.x, lane = tid & 63, wid = tid >> 6;
  int mt = blockIdx.x % tilesM, ntile = blockIdx.x / tilesM;
  int z = blockIdx.y, i0 = z / bdiv, i1 = z % bdiv;
  const u16* Ab = A + i0*aS0 + i1*aS1 + (size_t)mt*128*lda;
  const u16* Bb = Bm + i0*bS0 + i1*bS1 + (size_t)ntile*128*ldb;

  f32x4 acc[4][4];
  #pragma unroll
  for (int i=0;i<4;i++)
    #pragma unroll
    for (int j=0;j<4;j++) acc[i][j] = (f32x4){0.f,0.f,0.f,0.f};

  int wm = (wid & 1)*64, wn = (wid >> 1)*64;
  int r8 = lane >> 3;                  // row within 8-row chunk
  int s8 = (lane & 7) ^ r8;            // pre-swizzled source 16B slot

  for (int k0 = 0; k0 < Kc; k0 += 64){
    __syncthreads();
    #pragma unroll
    for (int c = 0; c < 4; ++c){
      int cc = wid + c*4;              // chunk 0..15 (8 rows x 128B each)
      int row = cc*8 + r8;
      gload16(Ab + (size_t)row*lda + k0 + s8*8, &lA[cc*512]);
      gload16(Bb + (size_t)row*ldb + k0 + s8*8, &lB[cc*512]);
    }
    __syncthreads();
    #pragma unroll
    for (int kk = 0; kk < 2; ++kk){
      bf16x8 af[4], bfr[4];
      #pragma unroll
      for (int i=0;i<4;i++){
        int row = wm + i*16 + (lane & 15);
        int sl = ((kk<<2) + (lane >> 4)) ^ (row & 7);
        af[i] = *(const bf16x8*)&lA[row*64 + sl*8];
      }
      #pragma unroll
      for (int j=0;j<4;j++){
        int row = wn + j*16 + (lane & 15);
        int sl = ((kk<<2) + (lane >> 4)) ^ (row & 7);
        bfr[j] = *(const bf16x8*)&lB[row*64 + sl*8];
      }
      #pragma unroll
      for (int i=0;i<4;i++)
        #pragma unroll
        for (int j=0;j<4;j++)
          acc[i][j] = __builtin_amdgcn_mfma_f32_16x16x32_bf16(af[i], bfr[j], acc[i][j], 0,0,0);
    }
  }
  int g = lane >> 4, c16 = lane & 15;
  if constexpr (CMODE == 0){
    u16* Cb = (u16*)Cm + i0*cS0 + i1*cS1;
    #pragma unroll
    for (int j=0;j<4;j++){
      int n = ntile*128 + wn + j*16 + c16;
      if (n >= Nmax) continue;
      float bv = 0.f;
      if (BIAS) bv = bias[(size_t)i0*biasS0 + n];
      #pragma unroll
      for (int i=0;i<4;i++){
        int mb = mt*128 + wm + i*16 + g*4;
        #pragma unroll
        for (int r=0;r<4;r++){
          float v = (acc[i][j][r] + bv)*scale;
          Cb[(size_t)(mb + r)*ldc + n] = f2b(v);
        }
      }
    }
  } else {
    float* Cb = (float*)Cm + i0*cS0 + i1*cS1;
    #pragma unroll
    for (int j=0;j<4;j++){
      int n = ntile*128 + wn + j*16 + c16;
      #pragma unroll
      for (int i=0;i<4;i++){
        int mb = mt*128 + wm + i*16 + g*4;
        float* p = Cb + (size_t)n*ldc + mb;
        float4 v;
        v.x = acc[i][j][0]; v.y = acc[i][j][1]; v.z = acc[i][j][2]; v.w = acc[i][j][3];
        if (ACC){
          float4 old = *(const float4*)p;
          v.x += old.x; v.y += old.y; v.z += old.z; v.w += old.w;
        }
        *(float4*)p = v;
      }
    }
  }
}

// ---------------- fused QK^T + softmax -> attn bf16 [B][LQ][448] (per h,s) ----------------
__global__ __launch_bounds__(256) void k_scores(
    const u16* __restrict__ qws, const u16* __restrict__ kws,
    u16* __restrict__ attn, int h, int s){
  __shared__ __align__(16) u16 lQ[64*64];
  __shared__ __align__(16) u16 lK[400*64];
  int tid = threadIdx.x, lane = tid & 63, wid = tid >> 6;
  int m0 = blockIdx.x * 64;
  int b = blockIdx.y;
  const u16* Qp = qws + ((size_t)(h*B_ + b)*LQ + m0)*D_;
  const u16* Kp = kws + ((size_t)((h*S_ + s)*B_ + b))*((size_t)LKM*D_);
  int r8 = lane >> 3, s8 = (lane & 7) ^ r8;
  f32x4 acc[25];
  #pragma unroll
  for (int t=0;t<25;t++) acc[t] = (f32x4){0.f,0.f,0.f,0.f};
  int wm = wid * 16;
  for (int k0 = 0; k0 < 256; k0 += 64){
    __syncthreads();
    #pragma unroll
    for (int c = 0; c < 2; ++c){
      int cc = wid + c*4;
      int row = cc*8 + r8;
      gload16(Qp + (size_t)row*D_ + k0 + s8*8, &lQ[cc*512]);
    }
    for (int cc = wid; cc < 50; cc += 4){
      int row = cc*8 + r8;
      gload16(Kp + (size_t)row*D_ + k0 + s8*8, &lK[cc*512]);
    }
    __syncthreads();
    #pragma unroll
    for (int kk = 0; kk < 2; ++kk){
      int rowA = wm + (lane & 15);
      int slA = ((kk<<2) + (lane>>4)) ^ (rowA & 7);
      bf16x8 af = *(const bf16x8*)&lQ[rowA*64 + slA*8];
      #pragma unroll
      for (int t=0;t<25;t++){
        int rowB = t*16 + (lane & 15);
        int slB = ((kk<<2) + (lane>>4)) ^ (rowB & 7);
        bf16x8 bf = *(const bf16x8*)&lK[rowB*64 + slB*8];
        acc[t] = __builtin_amdgcn_mfma_f32_16x16x32_bf16(af, bf, acc[t], 0,0,0);
      }
    }
  }
  // row-wise softmax over 400 cols (scores pre-scaled by 1/16 via q)
  float mx[4] = {-1e30f,-1e30f,-1e30f,-1e30f};
  #pragma unroll
  for (int t=0;t<25;t++)
    #pragma unroll
    for (int r=0;r<4;r++) mx[r] = fmaxf(mx[r], acc[t][r]);
  #pragma unroll
  for (int r=0;r<4;r++){
    mx[r] = fmaxf(mx[r], __shfl_xor(mx[r], 1));
    mx[r] = fmaxf(mx[r], __shfl_xor(mx[r], 2));
    mx[r] = fmaxf(mx[r], __shfl_xor(mx[r], 4));
    mx[r] = fmaxf(mx[r], __shfl_xor(mx[r], 8));
  }
  float sm[4] = {0.f,0.f,0.f,0.f};
  #pragma unroll
  for (int t=0;t<25;t++)
    #pragma unroll
    for (int r=0;r<4;r++){ float e = __expf(acc[t][r] - mx[r]); acc[t][r] = e; sm[r] += e; }
  #pragma unroll
  for (int r=0;r<4;r++){
    sm[r] += __shfl_xor(sm[r], 1);
    sm[r] += __shfl_xor(sm[r], 2);
    sm[r] += __shfl_xor(sm[r], 4);
    sm[r] += __shfl_xor(sm[r], 8);
    sm[r] = 1.f / sm[r];
  }
  u16* ap = attn + ((size_t)b*LQ + m0 + wm)*LKP;
  int g = lane >> 4, c16 = lane & 15;
  #pragma unroll
  for (int t=0;t<25;t++)
    #pragma unroll
    for (int r=0;r<4;r++)
      ap[(size_t)(g*4 + r)*LKP + t*16 + c16] = f2b(acc[t][r] * sm[r]);
  for (int t = lane; t < 16*48; t += 64){
    int rr = t / 48, cp = 400 + (t % 48);
    ap[(size_t)rr*LKP + cp] = 0;
  }
}

// ---------------- in-place: out = base * relu(0.2*attAcc + Mb[c]) ----------------
__global__ __launch_bounds__(256) void k_final(const float* __restrict__ base, const float* __restrict__ Mb, float* __restrict__ out){
  int i = blockIdx.x*256 + threadIdx.x;         // float4 index over [B][C][LQ]
  int c = (i >> 10) & 1023;                     // LQ/4 = 1024 float4 per (b,c) row
  float4 a = ((const float4*)out)[i];
  float4 bs = ((const float4*)base)[i];
  float m = Mb[c];
  float4 r;
  r.x = bs.x * fmaxf(0.2f*a.x + m, 0.f);
  r.y = bs.y * fmaxf(0.2f*a.y + m, 0.f);
  r.z = bs.z * fmaxf(0.2f*a.z + m, 0.f);
  r.w = bs.w * fmaxf(0.2f*a.w + m, 0.f);
  ((float4*)out)[i] = r;
}

extern "C" void kernel_launch(void* const* d_in, const int* in_sizes, int n_in,
                              void* d_out, int out_size, void* d_ws, size_t ws_size,
                              hipStream_t stream){
  const float* base = (const float*)d_in[0];
  const float* sup  = (const float*)d_in[1];
  const float* Qw   = (const float*)d_in[2];
  const float* Qb   = (const float*)d_in[3];
  const float* Kw   = (const float*)d_in[4];
  const float* Kb   = (const float*)d_in[5];
  const float* Mw   = (const float*)d_in[6];
  const float* Mb   = (const float*)d_in[7];
  float* out = (float*)d_out;
  char* ws = (char*)d_ws;

  // workspace layout (bytes) — total 121,634,816 (~116 MiB)
  u16* wQw = (u16*)(ws + 0);            //  2,097,152  [H][D][C]
  u16* wKw = (u16*)(ws + 2097152);      //  2,097,152  [H][D][C]
  u16* wMw = (u16*)(ws + 4194304);      //  8,388,608  [C][H*C]
  u16* wKC = (u16*)(ws + 12582912);     // 20,971,520  smat [S][B][512][C]
  u16* wK  = (u16*)(ws + 33554432);     // 20,971,520  k [H][S][B][512][D]
  u16* wQ  = (u16*)(ws + 54525952);     // 33,554,432  q [H][B][LQ][D]
  u16* wXb = (u16*)(ws + 88080384);     // 33,554,432  Xb [B][LQ][C] (dead after q-proj)
  u16* wATs = (u16*)(ws + 88080384);    // 14,680,064  attn [B][LQ][448]   (aliases Xb)
  u16* wVt  = (u16*)(ws + 102760448);   // 18,350,080  Vt [S][B][C][448]   (aliases Xb)

  const int BIG = 1 << 30;

  k_cvt<<<1024, 256, 0, stream>>>(Qw, wQw, 262144);
  k_cvt<<<1024, 256, 0, stream>>>(Kw, wKw, 262144);
  k_cvt<<<4096, 256, 0, stream>>>(Mw, wMw, 1048576);
  k_transpose_x<<<dim3(128, 32, 4), 256, 0, stream>>>(base, wXb);
  k_build_smat<<<dim3(16, 32, 20), 256, 0, stream>>>(sup, wKC);

  // k-proj: k[h][s][b] = smat[s][b] @ Kw[h]^T + Kb   (M=512, N=256, K=1024)
  k_gemm<0,false,true><<<dim3(8, 80), 256, 0, stream>>>(
      wKC, wKw, wK, Kb, 4, C_, C_, D_, C_,
      20, 0, (int64_t)LKM*C_, (int64_t)D_*C_, 0,
      (int64_t)S_*B_*LKM*D_, (int64_t)LKM*D_, D_, 1.f, BIG);

  // q-proj: q[h][b] = (Xb[b] @ Qw[h]^T + Qb)/16      (M=4096, N=256, K=1024)
  k_gemm<0,false,true><<<dim3(64, 16), 256, 0, stream>>>(
      wXb, wQw, wQ, Qb, 32, C_, C_, D_, C_,
      4, 0, (int64_t)LQ*C_, (int64_t)D_*C_, 0,
      (int64_t)B_*LQ*D_, (int64_t)LQ*D_, D_, 1.f/16.f, BIG);

  for (int h = 0; h < H_; ++h){
    // Vt[s][b][c][k] = sum_c' Mw[c][h*C+c'] * smat[s][b][k][c']   (M=1024, N=512->448, K=1024)
    k_gemm<0,false,false><<<dim3(32, 20), 256, 0, stream>>>(
        wMw + (size_t)h*C_, wKC, wVt, nullptr, 8, H_*C_, C_, LKP, C_,
        4, 0, 0, (int64_t)B_*LKM*C_, (int64_t)LKM*C_,
        (int64_t)B_*C_*LKP, (int64_t)C_*LKP, 0, 1.f, LKP);

    for (int s = 0; s < S_; ++s){
      k_scores<<<dim3(64, 4), 256, 0, stream>>>(wQ, wK, wATs, h, s);
      // attAcc[b][c][l] (+)= attn[b][l][:] . Vt[s][b][c][:]   (M=4096, N=1024, K=448)
      if (h == 0 && s == 0){
        k_gemm<1,false,false><<<dim3(256, 4), 256, 0, stream>>>(
            wATs, wVt + (size_t)s*B_*C_*LKP, out, nullptr, 32, LKP, LKP, LQ, LKP,
            4, 0, (int64_t)LQ*LKP, 0, (int64_t)C_*LKP,
            0, (int64_t)C_*LQ, 0, 1.f, BIG);
      } else {
        k_gemm<1,true,false><<<dim3(256, 4), 256, 0, stream>>>(
            wATs, wVt + (size_t)s*B_*C_*LKP, out, nullptr, 32, LKP, LKP, LQ, LKP,
            4, 0, (int64_t)LQ*LKP, 0, (int64_t)C_*LKP,
            0, (int64_t)C_*LQ, 0, 1.f, BIG);
      }
    }
  }

  k_final<<<16384, 256, 0, stream>>>(base, Mb, out);
}

// Round 3
// 906.337 us; speedup vs baseline: 1.4803x; 1.4803x over previous
//
#include <hip/hip_runtime.h>
#include <stdint.h>

#define DEVI __device__ __forceinline__

typedef __attribute__((ext_vector_type(8))) short bf16x8;
typedef __attribute__((ext_vector_type(4))) float f32x4;
typedef __attribute__((ext_vector_type(4))) unsigned short us4;
typedef unsigned short u16;

constexpr int B_ = 4, S_ = 5, H_ = 4, C_ = 1024, D_ = 256;
constexpr int LQ = 4096, LK = 400, LKP = 448, LKM = 512;

DEVI u16 f2b(float f){
  uint32_t x = __float_as_uint(f);
  uint32_t r = (x + 0x7FFFu + ((x >> 16) & 1u)) >> 16;
  return (u16)r;
}

typedef __attribute__((address_space(1))) const void ASG;
typedef __attribute__((address_space(3))) void ASL;
DEVI void gload16(const void* g, void* l){
  __builtin_amdgcn_global_load_lds((ASG*)g, (ASL*)l, 16, 0, 0);
}

// ---------------- fp32 -> bf16 convert ----------------
__global__ __launch_bounds__(256) void k_cvt(const float* __restrict__ s, u16* __restrict__ d, int n4){
  int i = blockIdx.x*256 + threadIdx.x;
  if (i >= n4) return;
  float4 v = ((const float4*)s)[i];
  us4 o; o.x = f2b(v.x); o.y = f2b(v.y); o.z = f2b(v.z); o.w = f2b(v.w);
  *(us4*)(d + (size_t)i*4) = o;
}

// ---------------- base_feat [B][C][LQ] -> Xb bf16 [B][LQ][C] ----------------
__global__ __launch_bounds__(256) void k_transpose_x(const float* __restrict__ base, u16* __restrict__ Xb){
  __shared__ float t[32][33];
  int l0 = blockIdx.x*32, c0 = blockIdx.y*32, b = blockIdx.z;
  int tx = threadIdx.x & 31, ty = threadIdx.x >> 5;
  const float* src = base + ((size_t)b*C_ + c0)*LQ + l0;
  #pragma unroll
  for (int i=0;i<4;i++){ int cc = ty + i*8; t[cc][tx] = src[(size_t)cc*LQ + tx]; }
  __syncthreads();
  u16* dst = Xb + ((size_t)b*LQ + l0)*C_ + c0;
  #pragma unroll
  for (int i=0;i<4;i++){ int ll = ty + i*8; dst[(size_t)ll*C_ + tx] = f2b(t[tx][ll]); }
}

// ---------------- support + pe -> smat_kc [S][B][512][C] (rows 400..511 zero) ----------------
__global__ __launch_bounds__(256) void k_build_smat(const float* __restrict__ sup, u16* __restrict__ kc){
  __shared__ float t[32][33];
  int p0 = blockIdx.x*32, c0 = blockIdx.y*32;
  int s = blockIdx.z / B_, b = blockIdx.z % B_;
  int tx = threadIdx.x & 31, ty = threadIdx.x >> 5;
  const float* src = sup + ((size_t)(b*S_ + s)*C_ + c0)*LK + p0;
  #pragma unroll
  for (int i=0;i<4;i++){
    int cc = ty + i*8;
    int p = p0 + tx;
    int c = c0 + cc;
    float v = 0.f;
    if (p < LK){
      v = src[(size_t)cc*LK + tx];
      float dv = expf(-(float)(c & ~1) * (9.210340371976184f / 1024.f));
      float arg = (float)p * dv;
      v += (c & 1) ? cosf(arg) : sinf(arg);
    }
    t[cc][tx] = v;
  }
  __syncthreads();
  u16* dkc = kc + ((size_t)((s*B_ + b)*LKM + p0))*C_ + c0;
  #pragma unroll
  for (int i=0;i<4;i++){ int pp = ty + i*8; dkc[(size_t)pp*C_ + tx] = f2b(t[tx][pp]); }
}

// ---------------- generic bf16 MFMA GEMM: C[M][N] = sum_ch A_ch[M][K] * B_ch[N][K]^T ----------------
// 128x128 tile, 4 waves (2x2 of 64x64), BK=64, global_load_lds with pre-swizzled source.
// CMODE 0: bf16 row-major store C[m*ldc+n]. CMODE 1: fp32 transposed store C[n*ldc+m] (+=old if ACC).
template<int CMODE, bool ACC, bool BIAS>
__global__ __launch_bounds__(256) void k_gemm(
    const u16* __restrict__ A, const u16* __restrict__ Bm, void* __restrict__ Cm,
    const float* __restrict__ bias,
    int tilesM, int lda, int ldb, int ldc, int Kc,
    int nChunks, int64_t aChunk, int64_t bChunk,
    int bdiv, int64_t aS0, int64_t aS1, int64_t bS0, int64_t bS1,
    int64_t cS0, int64_t cS1, int biasS0, float scale, int Nmax){
  __shared__ __align__(16) u16 lA[128*64];
  __shared__ __align__(16) u16 lB[128*64];
  int tid = threadIdx.x, lane = tid & 63, wid = tid >> 6;
  int mt = blockIdx.x % tilesM, ntile = blockIdx.x / tilesM;
  int z = blockIdx.y, i0 = z / bdiv, i1 = z % bdiv;
  const u16* Ab = A + i0*aS0 + i1*aS1 + (size_t)mt*128*lda;
  const u16* Bb = Bm + i0*bS0 + i1*bS1 + (size_t)ntile*128*ldb;

  f32x4 acc[4][4];
  #pragma unroll
  for (int i=0;i<4;i++)
    #pragma unroll
    for (int j=0;j<4;j++) acc[i][j] = (f32x4){0.f,0.f,0.f,0.f};

  int wm = (wid & 1)*64, wn = (wid >> 1)*64;
  int r8 = lane >> 3;                  // row within 8-row chunk
  int s8 = (lane & 7) ^ r8;            // pre-swizzled source 16B slot

  for (int ch = 0; ch < nChunks; ++ch){
    const u16* Ac = Ab + (size_t)ch*aChunk;
    const u16* Bc = Bb + (size_t)ch*bChunk;
    for (int k0 = 0; k0 < Kc; k0 += 64){
      __syncthreads();
      #pragma unroll
      for (int c = 0; c < 4; ++c){
        int cc = wid + c*4;            // chunk 0..15 (8 rows x 128B each)
        int row = cc*8 + r8;
        gload16(Ac + (size_t)row*lda + k0 + s8*8, &lA[cc*512]);
        gload16(Bc + (size_t)row*ldb + k0 + s8*8, &lB[cc*512]);
      }
      __syncthreads();
      #pragma unroll
      for (int kk = 0; kk < 2; ++kk){
        bf16x8 af[4], bfr[4];
        #pragma unroll
        for (int i=0;i<4;i++){
          int row = wm + i*16 + (lane & 15);
          int sl = ((kk<<2) + (lane >> 4)) ^ (row & 7);
          af[i] = *(const bf16x8*)&lA[row*64 + sl*8];
        }
        #pragma unroll
        for (int j=0;j<4;j++){
          int row = wn + j*16 + (lane & 15);
          int sl = ((kk<<2) + (lane >> 4)) ^ (row & 7);
          bfr[j] = *(const bf16x8*)&lB[row*64 + sl*8];
        }
        #pragma unroll
        for (int i=0;i<4;i++)
          #pragma unroll
          for (int j=0;j<4;j++)
            acc[i][j] = __builtin_amdgcn_mfma_f32_16x16x32_bf16(af[i], bfr[j], acc[i][j], 0,0,0);
      }
    }
  }
  int g = lane >> 4, c16 = lane & 15;
  if constexpr (CMODE == 0){
    u16* Cb = (u16*)Cm + i0*cS0 + i1*cS1;
    #pragma unroll
    for (int j=0;j<4;j++){
      int n = ntile*128 + wn + j*16 + c16;
      if (n >= Nmax) continue;
      float bv = 0.f;
      if (BIAS) bv = bias[(size_t)i0*biasS0 + n];
      #pragma unroll
      for (int i=0;i<4;i++){
        int mb = mt*128 + wm + i*16 + g*4;
        #pragma unroll
        for (int r=0;r<4;r++){
          float v = (acc[i][j][r] + bv)*scale;
          Cb[(size_t)(mb + r)*ldc + n] = f2b(v);
        }
      }
    }
  } else {
    float* Cb = (float*)Cm + i0*cS0 + i1*cS1;
    #pragma unroll
    for (int j=0;j<4;j++){
      int n = ntile*128 + wn + j*16 + c16;
      #pragma unroll
      for (int i=0;i<4;i++){
        int mb = mt*128 + wm + i*16 + g*4;
        float* p = Cb + (size_t)n*ldc + mb;
        float4 v;
        v.x = acc[i][j][0]; v.y = acc[i][j][1]; v.z = acc[i][j][2]; v.w = acc[i][j][3];
        if (ACC){
          float4 old = *(const float4*)p;
          v.x += old.x; v.y += old.y; v.z += old.z; v.w += old.w;
        }
        *(float4*)p = v;
      }
    }
  }
}

// ---------------- fused QK^T + softmax -> attn bf16 [S][B][LQ][448] (per h, all s) ----------------
__global__ __launch_bounds__(256) void k_scores(
    const u16* __restrict__ qws, const u16* __restrict__ kws,
    u16* __restrict__ attn, int h){
  __shared__ __align__(16) u16 lQ[64*64];
  __shared__ __align__(16) u16 lK[400*64];
  int tid = threadIdx.x, lane = tid & 63, wid = tid >> 6;
  int m0 = blockIdx.x * 64;
  int b = blockIdx.y;
  int s = blockIdx.z;
  const u16* Qp = qws + ((size_t)(h*B_ + b)*LQ + m0)*D_;
  const u16* Kp = kws + ((size_t)((h*S_ + s)*B_ + b))*((size_t)LKM*D_);
  int r8 = lane >> 3, s8 = (lane & 7) ^ r8;
  f32x4 acc[25];
  #pragma unroll
  for (int t=0;t<25;t++) acc[t] = (f32x4){0.f,0.f,0.f,0.f};
  int wm = wid * 16;
  for (int k0 = 0; k0 < 256; k0 += 64){
    __syncthreads();
    #pragma unroll
    for (int c = 0; c < 2; ++c){
      int cc = wid + c*4;
      int row = cc*8 + r8;
      gload16(Qp + (size_t)row*D_ + k0 + s8*8, &lQ[cc*512]);
    }
    for (int cc = wid; cc < 50; cc += 4){
      int row = cc*8 + r8;
      gload16(Kp + (size_t)row*D_ + k0 + s8*8, &lK[cc*512]);
    }
    __syncthreads();
    #pragma unroll
    for (int kk = 0; kk < 2; ++kk){
      int rowA = wm + (lane & 15);
      int slA = ((kk<<2) + (lane>>4)) ^ (rowA & 7);
      bf16x8 af = *(const bf16x8*)&lQ[rowA*64 + slA*8];
      #pragma unroll
      for (int t=0;t<25;t++){
        int rowB = t*16 + (lane & 15);
        int slB = ((kk<<2) + (lane>>4)) ^ (rowB & 7);
        bf16x8 bf = *(const bf16x8*)&lK[rowB*64 + slB*8];
        acc[t] = __builtin_amdgcn_mfma_f32_16x16x32_bf16(af, bf, acc[t], 0,0,0);
      }
    }
  }
  // row-wise softmax over 400 cols (scores pre-scaled by 1/16 via q)
  float mx[4] = {-1e30f,-1e30f,-1e30f,-1e30f};
  #pragma unroll
  for (int t=0;t<25;t++)
    #pragma unroll
    for (int r=0;r<4;r++) mx[r] = fmaxf(mx[r], acc[t][r]);
  #pragma unroll
  for (int r=0;r<4;r++){
    mx[r] = fmaxf(mx[r], __shfl_xor(mx[r], 1));
    mx[r] = fmaxf(mx[r], __shfl_xor(mx[r], 2));
    mx[r] = fmaxf(mx[r], __shfl_xor(mx[r], 4));
    mx[r] = fmaxf(mx[r], __shfl_xor(mx[r], 8));
  }
  float sm[4] = {0.f,0.f,0.f,0.f};
  #pragma unroll
  for (int t=0;t<25;t++)
    #pragma unroll
    for (int r=0;r<4;r++){ float e = __expf(acc[t][r] - mx[r]); acc[t][r] = e; sm[r] += e; }
  #pragma unroll
  for (int r=0;r<4;r++){
    sm[r] += __shfl_xor(sm[r], 1);
    sm[r] += __shfl_xor(sm[r], 2);
    sm[r] += __shfl_xor(sm[r], 4);
    sm[r] += __shfl_xor(sm[r], 8);
    sm[r] = 1.f / sm[r];
  }
  u16* ap = attn + ((size_t)((s*B_ + b)*LQ) + m0 + wm)*LKP;
  int g = lane >> 4, c16 = lane & 15;
  #pragma unroll
  for (int t=0;t<25;t++)
    #pragma unroll
    for (int r=0;r<4;r++)
      ap[(size_t)(g*4 + r)*LKP + t*16 + c16] = f2b(acc[t][r] * sm[r]);
  for (int t = lane; t < 16*48; t += 64){
    int rr = t / 48, cp = 400 + (t % 48);
    ap[(size_t)rr*LKP + cp] = 0;
  }
}

// ---------------- in-place: out = base * relu(0.2*attAcc + Mb[c]) ----------------
__global__ __launch_bounds__(256) void k_final(const float* __restrict__ base, const float* __restrict__ Mb, float* __restrict__ out){
  int i = blockIdx.x*256 + threadIdx.x;         // float4 index over [B][C][LQ]
  int c = (i >> 10) & 1023;                     // LQ/4 = 1024 float4 per (b,c) row
  float4 a = ((const float4*)out)[i];
  float4 bs = ((const float4*)base)[i];
  float m = Mb[c];
  float4 r;
  r.x = bs.x * fmaxf(0.2f*a.x + m, 0.f);
  r.y = bs.y * fmaxf(0.2f*a.y + m, 0.f);
  r.z = bs.z * fmaxf(0.2f*a.z + m, 0.f);
  r.w = bs.w * fmaxf(0.2f*a.w + m, 0.f);
  ((float4*)out)[i] = r;
}

extern "C" void kernel_launch(void* const* d_in, const int* in_sizes, int n_in,
                              void* d_out, int out_size, void* d_ws, size_t ws_size,
                              hipStream_t stream){
  const float* base = (const float*)d_in[0];
  const float* sup  = (const float*)d_in[1];
  const float* Qw   = (const float*)d_in[2];
  const float* Qb   = (const float*)d_in[3];
  const float* Kw   = (const float*)d_in[4];
  const float* Kb   = (const float*)d_in[5];
  const float* Mw   = (const float*)d_in[6];
  const float* Mb   = (const float*)d_in[7];
  float* out = (float*)d_out;
  char* ws = (char*)d_ws;

  // workspace layout (bytes) — total 179,830,784 (~171.5 MiB)
  u16* wQw = (u16*)(ws + 0);            //  2,097,152  [H][D][C]
  u16* wKw = (u16*)(ws + 2097152);      //  2,097,152  [H][D][C]
  u16* wMw = (u16*)(ws + 4194304);      //  8,388,608  [C][H*C]
  u16* wKC = (u16*)(ws + 12582912);     // 20,971,520  smat [S][B][512][C]
  u16* wK  = (u16*)(ws + 33554432);     // 20,971,520  k [H][S][B][512][D]
  u16* wQ  = (u16*)(ws + 54525952);     // 33,554,432  q [H][B][LQ][D]
  u16* wVt = (u16*)(ws + 88080384);     // 18,350,080  Vt [S][B][C][448] (per h)
  u16* wXb = (u16*)(ws + 106430464);    // 33,554,432  Xb [B][LQ][C] (dead after q-proj)
  u16* wATs = (u16*)(ws + 106430464);   // 73,400,320  attn [S][B][LQ][448] (per h; aliases Xb)

  const int BIG = 1 << 30;

  k_cvt<<<1024, 256, 0, stream>>>(Qw, wQw, 262144);
  k_cvt<<<1024, 256, 0, stream>>>(Kw, wKw, 262144);
  k_cvt<<<4096, 256, 0, stream>>>(Mw, wMw, 1048576);
  k_transpose_x<<<dim3(128, 32, 4), 256, 0, stream>>>(base, wXb);
  k_build_smat<<<dim3(16, 32, 20), 256, 0, stream>>>(sup, wKC);

  // k-proj: k[h][s][b] = smat[s][b] @ Kw[h]^T + Kb   (M=512, N=256, K=1024)
  k_gemm<0,false,true><<<dim3(8, 80), 256, 0, stream>>>(
      wKC, wKw, wK, Kb, 4, C_, C_, D_, C_,
      1, 0, 0,
      20, 0, (int64_t)LKM*C_, (int64_t)D_*C_, 0,
      (int64_t)S_*B_*LKM*D_, (int64_t)LKM*D_, D_, 1.f, BIG);

  // q-proj: q[h][b] = (Xb[b] @ Qw[h]^T + Qb)/16      (M=4096, N=256, K=1024)
  k_gemm<0,false,true><<<dim3(64, 16), 256, 0, stream>>>(
      wXb, wQw, wQ, Qb, 32, C_, C_, D_, C_,
      1, 0, 0,
      4, 0, (int64_t)LQ*C_, (int64_t)D_*C_, 0,
      (int64_t)B_*LQ*D_, (int64_t)LQ*D_, D_, 1.f/16.f, BIG);

  for (int h = 0; h < H_; ++h){
    // Vt[s][b][c][k] = sum_c' Mw[c][h*C+c'] * smat[s][b][k][c']  (M=1024, N=512->448, K=1024)
    k_gemm<0,false,false><<<dim3(32, 20), 256, 0, stream>>>(
        wMw + (size_t)h*C_, wKC, wVt, nullptr, 8, H_*C_, C_, LKP, C_,
        1, 0, 0,
        4, 0, 0, (int64_t)B_*LKM*C_, (int64_t)LKM*C_,
        (int64_t)B_*C_*LKP, (int64_t)C_*LKP, 0, 1.f, LKP);

    // scores+softmax for all s of this h
    k_scores<<<dim3(64, 4, 5), 256, 0, stream>>>(wQ, wK, wATs, h);

    // attAcc[b][c][l] (+)= sum_s attn[s][b][l][:] . Vt[s][b][c][:]  (M=4096, N=1024, K=5*448)
    if (h == 0){
      k_gemm<1,false,false><<<dim3(256, 4), 256, 0, stream>>>(
          wATs, wVt, out, nullptr, 32, LKP, LKP, LQ, LKP,
          5, (int64_t)B_*LQ*LKP, (int64_t)B_*C_*LKP,
          4, 0, (int64_t)LQ*LKP, 0, (int64_t)C_*LKP,
          0, (int64_t)C_*LQ, 0, 1.f, BIG);
    } else {
      k_gemm<1,true,false><<<dim3(256, 4), 256, 0, stream>>>(
          wATs, wVt, out, nullptr, 32, LKP, LKP, LQ, LKP,
          5, (int64_t)B_*LQ*LKP, (int64_t)B_*C_*LKP,
          4, 0, (int64_t)LQ*LKP, 0, (int64_t)C_*LKP,
          0, (int64_t)C_*LQ, 0, 1.f, BIG);
    }
  }

  k_final<<<16384, 256, 0, stream>>>(base, Mb, out);
}

// Round 4
// 822.999 us; speedup vs baseline: 1.6302x; 1.1013x over previous
//
#include <hip/hip_runtime.h>
#include <stdint.h>

#define DEVI __device__ __forceinline__

typedef __attribute__((ext_vector_type(8))) short bf16x8;
typedef __attribute__((ext_vector_type(4))) float f32x4;
typedef __attribute__((ext_vector_type(4))) unsigned short us4;
typedef unsigned short u16;

constexpr int B_ = 4, S_ = 5, H_ = 4, C_ = 1024, D_ = 256;
constexpr int LQ = 4096, LK = 400, LKP = 448, LKM = 512;

DEVI u16 f2b(float f){
  uint32_t x = __float_as_uint(f);
  uint32_t r = (x + 0x7FFFu + ((x >> 16) & 1u)) >> 16;
  return (u16)r;
}

typedef __attribute__((address_space(1))) const void ASG;
typedef __attribute__((address_space(3))) void ASL;
DEVI void gload16(const void* g, void* l){
  __builtin_amdgcn_global_load_lds((ASG*)g, (ASL*)l, 16, 0, 0);
}

// ---------------- fp32 -> bf16 convert ----------------
__global__ __launch_bounds__(256) void k_cvt(const float* __restrict__ s, u16* __restrict__ d, int n4){
  int i = blockIdx.x*256 + threadIdx.x;
  if (i >= n4) return;
  float4 v = ((const float4*)s)[i];
  us4 o; o.x = f2b(v.x); o.y = f2b(v.y); o.z = f2b(v.z); o.w = f2b(v.w);
  *(us4*)(d + (size_t)i*4) = o;
}

// ---------------- base_feat [B][C][LQ] -> Xb bf16 [B][LQ][C] ----------------
__global__ __launch_bounds__(256) void k_transpose_x(const float* __restrict__ base, u16* __restrict__ Xb){
  __shared__ float t[32][33];
  int l0 = blockIdx.x*32, c0 = blockIdx.y*32, b = blockIdx.z;
  int tx = threadIdx.x & 31, ty = threadIdx.x >> 5;
  const float* src = base + ((size_t)b*C_ + c0)*LQ + l0;
  #pragma unroll
  for (int i=0;i<4;i++){ int cc = ty + i*8; t[cc][tx] = src[(size_t)cc*LQ + tx]; }
  __syncthreads();
  u16* dst = Xb + ((size_t)b*LQ + l0)*C_ + c0;
  #pragma unroll
  for (int i=0;i<4;i++){ int ll = ty + i*8; dst[(size_t)ll*C_ + tx] = f2b(t[tx][ll]); }
}

// ---------------- support + pe -> smat_kc [S][B][512][C] (rows 400..511 zero) ----------------
__global__ __launch_bounds__(256) void k_build_smat(const float* __restrict__ sup, u16* __restrict__ kc){
  __shared__ float t[32][33];
  int p0 = blockIdx.x*32, c0 = blockIdx.y*32;
  int s = blockIdx.z / B_, b = blockIdx.z % B_;
  int tx = threadIdx.x & 31, ty = threadIdx.x >> 5;
  const float* src = sup + ((size_t)(b*S_ + s)*C_ + c0)*LK + p0;
  #pragma unroll
  for (int i=0;i<4;i++){
    int cc = ty + i*8;
    int p = p0 + tx;
    int c = c0 + cc;
    float v = 0.f;
    if (p < LK){
      v = src[(size_t)cc*LK + tx];
      float dv = expf(-(float)(c & ~1) * (9.210340371976184f / 1024.f));
      float arg = (float)p * dv;
      v += (c & 1) ? cosf(arg) : sinf(arg);
    }
    t[cc][tx] = v;
  }
  __syncthreads();
  u16* dkc = kc + ((size_t)((s*B_ + b)*LKM + p0))*C_ + c0;
  #pragma unroll
  for (int i=0;i<4;i++){ int pp = ty + i*8; dkc[(size_t)pp*C_ + tx] = f2b(t[tx][pp]); }
}

// ================= 8-phase 256x256 bf16 MFMA GEMM engine =================
// C[M][N] = sum_ch A_ch[M][K] * B_ch[N][K]^T   (512 threads, 8 waves 2Mx4N)
// BK=64, 2x double-buffered LDS (128KB), counted vmcnt, setprio on MFMA.
// CEPI 0: bf16 row-major store C[m*ldc+n], (+bias)*scale, n<Nmax.
// CEPI 1: fp32 transposed store C[n*ldc+m] float4; FIRST: plain store,
//         else RMW add; FINAL: out = base*relu(0.2*(old+acc)+Mb[n]).
DEVI void stage_half(const u16* P, int64_t ld, u16* dst, int wid, int r8, int s8){
  #pragma unroll
  for (int it=0; it<2; ++it){
    int ck = wid + it*8;                              // 16 chunks of 8 rows
    gload16(P + (size_t)(ck*8 + r8)*ld + s8*8, dst + ck*512);
  }
}
DEVI bf16x8 ldsread(const u16* base, int row, int kk, int lane){
  int sl = ((kk<<2) + (lane>>4)) ^ (row & 7);
  return *(const bf16x8*)&base[row*64 + sl*8];
}

template<int CEPI, bool FIRST, bool FINAL, bool BIAS>
__global__ __launch_bounds__(512,1) void k8(
    const u16* __restrict__ A, const u16* __restrict__ Bm, void* __restrict__ Cm,
    const float* __restrict__ bias, const float* __restrict__ basep, const float* __restrict__ Mb,
    int tilesM, int64_t lda, int64_t ldb, int64_t ldc,
    int spc, int NT, int64_t aChunk, int64_t bChunk,
    int bdiv, int64_t aS0, int64_t aS1, int64_t bS0, int64_t bS1,
    int64_t cS0, int64_t cS1, int biasS0, float scale, int Nmax){
  __shared__ __align__(16) u16 lds[2][2][16384];      // [dbuf][A|B][256*64]
  int tid = threadIdx.x, lane = tid & 63, wid = tid >> 6;
  int mt = blockIdx.x % tilesM, ntile = blockIdx.x / tilesM;
  int z = blockIdx.y, i0 = z / bdiv, i1 = z % bdiv;
  const u16* Ab = A + i0*aS0 + i1*aS1 + (size_t)mt*256*lda;
  const u16* Bb = Bm + i0*bS0 + i1*bS1 + (size_t)ntile*256*ldb;
  int r8 = lane >> 3, s8 = (lane & 7) ^ r8;
  int wr = wid >> 2, wc = wid & 3;                    // wave = (wr 0..1) x (wc 0..3)

  f32x4 acc[8][4];
  #pragma unroll
  for (int i=0;i<8;i++)
    #pragma unroll
    for (int j=0;j<4;j++) acc[i][j] = (f32x4){0.f,0.f,0.f,0.f};

  // prologue: stage K-tile 0 into buf 0
  const u16 *ApS = Ab, *BpS = Bb; int cs = 0;
  stage_half(ApS,                   lda, &lds[0][0][0],    wid, r8, s8);
  stage_half(ApS + (size_t)128*lda, lda, &lds[0][0][8192], wid, r8, s8);
  stage_half(BpS,                   ldb, &lds[0][1][0],    wid, r8, s8);
  stage_half(BpS + (size_t)128*ldb, ldb, &lds[0][1][8192], wid, r8, s8);
  ApS += 64; BpS += 64;
  if (++cs == spc){ cs = 0; ApS += aChunk - (int64_t)spc*64; BpS += bChunk - (int64_t)spc*64; }

  for (int t = 0; t < NT; ++t){
    int cur = t & 1, nxt = cur ^ 1;
    bool pf = (t + 1 < NT);
    const u16* lA = &lds[cur][0][0];
    const u16* lB = &lds[cur][1][0];
    u16* sA = &lds[nxt][0][0];
    u16* sB = &lds[nxt][1][0];
    bf16x8 bfr[4][2];
    #pragma unroll
    for (int p = 0; p < 4; ++p){
      if (p == 0){
        if (pf){
          stage_half(ApS, lda, sA, wid, r8, s8);
          asm volatile("s_waitcnt vmcnt(2)" ::: "memory");
        } else {
          asm volatile("s_waitcnt vmcnt(0)" ::: "memory");
        }
        asm volatile("s_barrier" ::: "memory");
        #pragma unroll
        for (int jn=0;jn<4;jn++)
          #pragma unroll
          for (int kk=0;kk<2;kk++)
            bfr[jn][kk] = ldsread(lB, wc*64 + jn*16 + (lane & 15), kk, lane);
      } else if (p == 1){
        if (pf) stage_half(ApS + (size_t)128*lda, lda, sA + 8192, wid, r8, s8);
      } else if (p == 2){
        if (pf) stage_half(BpS, ldb, sB, wid, r8, s8);
      } else {
        if (pf) stage_half(BpS + (size_t)128*ldb, ldb, sB + 8192, wid, r8, s8);
      }
      bf16x8 af[2][2];
      #pragma unroll
      for (int dm=0;dm<2;dm++)
        #pragma unroll
        for (int kk=0;kk<2;kk++)
          af[dm][kk] = ldsread(lA, wr*128 + (p*2+dm)*16 + (lane & 15), kk, lane);
      __builtin_amdgcn_s_setprio(1);
      #pragma unroll
      for (int dm=0;dm<2;dm++)
        #pragma unroll
        for (int jn=0;jn<4;jn++)
          #pragma unroll
          for (int kk=0;kk<2;kk++)
            acc[p*2+dm][jn] = __builtin_amdgcn_mfma_f32_16x16x32_bf16(af[dm][kk], bfr[jn][kk], acc[p*2+dm][jn], 0,0,0);
      __builtin_amdgcn_s_setprio(0);
      asm volatile("s_barrier" ::: "memory");
    }
    if (pf){
      ApS += 64; BpS += 64;
      if (++cs == spc){ cs = 0; ApS += aChunk - (int64_t)spc*64; BpS += bChunk - (int64_t)spc*64; }
    }
  }

  int g = lane >> 4, c16 = lane & 15;
  if constexpr (CEPI == 0){
    u16* Cb = (u16*)Cm + i0*cS0 + i1*cS1;
    #pragma unroll
    for (int jn=0;jn<4;jn++){
      int n = ntile*256 + wc*64 + jn*16 + c16;
      if (n >= Nmax) continue;
      float bv = 0.f;
      if (BIAS) bv = bias[(size_t)i0*biasS0 + n];
      #pragma unroll
      for (int im=0;im<8;im++){
        int m = mt*256 + wr*128 + im*16 + g*4;
        #pragma unroll
        for (int r=0;r<4;r++)
          Cb[(size_t)(m + r)*ldc + n] = f2b((acc[im][jn][r] + bv)*scale);
      }
    }
  } else {
    float* Cb = (float*)Cm + i0*cS0 + i1*cS1;
    const float* Bs = basep + i0*cS0 + i1*cS1;
    #pragma unroll
    for (int jn=0;jn<4;jn++){
      int n = ntile*256 + wc*64 + jn*16 + c16;
      float mbv = 0.f;
      if (FINAL) mbv = Mb[n];
      #pragma unroll
      for (int im=0;im<8;im++){
        int m = mt*256 + wr*128 + im*16 + g*4;
        float* p = Cb + (size_t)n*ldc + m;
        float4 v;
        v.x = acc[im][jn][0]; v.y = acc[im][jn][1]; v.z = acc[im][jn][2]; v.w = acc[im][jn][3];
        if (!FIRST){
          float4 old = *(const float4*)p;
          v.x += old.x; v.y += old.y; v.z += old.z; v.w += old.w;
        }
        if (FINAL){
          float4 bs = *(const float4*)(Bs + (size_t)n*ldc + m);
          v.x = bs.x * fmaxf(0.2f*v.x + mbv, 0.f);
          v.y = bs.y * fmaxf(0.2f*v.y + mbv, 0.f);
          v.z = bs.z * fmaxf(0.2f*v.z + mbv, 0.f);
          v.w = bs.w * fmaxf(0.2f*v.w + mbv, 0.f);
        }
        *(float4*)p = v;
      }
    }
  }
}

// ---------------- fused QK^T + softmax -> attn bf16 [S][B][LQ][448] (per h, all s) ----------------
__global__ __launch_bounds__(256) void k_scores(
    const u16* __restrict__ qws, const u16* __restrict__ kws,
    u16* __restrict__ attn, int h){
  __shared__ __align__(16) u16 lQ[64*64];
  __shared__ __align__(16) u16 lK[400*64];
  int tid = threadIdx.x, lane = tid & 63, wid = tid >> 6;
  int m0 = blockIdx.x * 64;
  int b = blockIdx.y;
  int s = blockIdx.z;
  const u16* Qp = qws + ((size_t)(h*B_ + b)*LQ + m0)*D_;
  const u16* Kp = kws + ((size_t)((h*S_ + s)*B_ + b))*((size_t)LKM*D_);
  int r8 = lane >> 3, s8 = (lane & 7) ^ r8;
  f32x4 acc[25];
  #pragma unroll
  for (int t=0;t<25;t++) acc[t] = (f32x4){0.f,0.f,0.f,0.f};
  int wm = wid * 16;
  for (int k0 = 0; k0 < 256; k0 += 64){
    __syncthreads();
    #pragma unroll
    for (int c = 0; c < 2; ++c){
      int cc = wid + c*4;
      int row = cc*8 + r8;
      gload16(Qp + (size_t)row*D_ + k0 + s8*8, &lQ[cc*512]);
    }
    for (int cc = wid; cc < 50; cc += 4){
      int row = cc*8 + r8;
      gload16(Kp + (size_t)row*D_ + k0 + s8*8, &lK[cc*512]);
    }
    __syncthreads();
    #pragma unroll
    for (int kk = 0; kk < 2; ++kk){
      int rowA = wm + (lane & 15);
      int slA = ((kk<<2) + (lane>>4)) ^ (rowA & 7);
      bf16x8 af = *(const bf16x8*)&lQ[rowA*64 + slA*8];
      #pragma unroll
      for (int t=0;t<25;t++){
        int rowB = t*16 + (lane & 15);
        int slB = ((kk<<2) + (lane>>4)) ^ (rowB & 7);
        bf16x8 bf = *(const bf16x8*)&lK[rowB*64 + slB*8];
        acc[t] = __builtin_amdgcn_mfma_f32_16x16x32_bf16(af, bf, acc[t], 0,0,0);
      }
    }
  }
  float mx[4] = {-1e30f,-1e30f,-1e30f,-1e30f};
  #pragma unroll
  for (int t=0;t<25;t++)
    #pragma unroll
    for (int r=0;r<4;r++) mx[r] = fmaxf(mx[r], acc[t][r]);
  #pragma unroll
  for (int r=0;r<4;r++){
    mx[r] = fmaxf(mx[r], __shfl_xor(mx[r], 1));
    mx[r] = fmaxf(mx[r], __shfl_xor(mx[r], 2));
    mx[r] = fmaxf(mx[r], __shfl_xor(mx[r], 4));
    mx[r] = fmaxf(mx[r], __shfl_xor(mx[r], 8));
  }
  float sm[4] = {0.f,0.f,0.f,0.f};
  #pragma unroll
  for (int t=0;t<25;t++)
    #pragma unroll
    for (int r=0;r<4;r++){ float e = __expf(acc[t][r] - mx[r]); acc[t][r] = e; sm[r] += e; }
  #pragma unroll
  for (int r=0;r<4;r++){
    sm[r] += __shfl_xor(sm[r], 1);
    sm[r] += __shfl_xor(sm[r], 2);
    sm[r] += __shfl_xor(sm[r], 4);
    sm[r] += __shfl_xor(sm[r], 8);
    sm[r] = 1.f / sm[r];
  }
  u16* ap = attn + ((size_t)((s*B_ + b)*LQ) + m0 + wm)*LKP;
  int g = lane >> 4, c16 = lane & 15;
  #pragma unroll
  for (int t=0;t<25;t++)
    #pragma unroll
    for (int r=0;r<4;r++)
      ap[(size_t)(g*4 + r)*LKP + t*16 + c16] = f2b(acc[t][r] * sm[r]);
  for (int t = lane; t < 16*48; t += 64){
    int rr = t / 48, cp = 400 + (t % 48);
    ap[(size_t)rr*LKP + cp] = 0;
  }
}

extern "C" void kernel_launch(void* const* d_in, const int* in_sizes, int n_in,
                              void* d_out, int out_size, void* d_ws, size_t ws_size,
                              hipStream_t stream){
  const float* base = (const float*)d_in[0];
  const float* sup  = (const float*)d_in[1];
  const float* Qw   = (const float*)d_in[2];
  const float* Qb   = (const float*)d_in[3];
  const float* Kw   = (const float*)d_in[4];
  const float* Kb   = (const float*)d_in[5];
  const float* Mw   = (const float*)d_in[6];
  const float* Mb   = (const float*)d_in[7];
  float* out = (float*)d_out;
  char* ws = (char*)d_ws;

  // workspace layout (bytes) — total 179,830,784 (~171.5 MiB)
  u16* wQw = (u16*)(ws + 0);            //  2,097,152  [H][D][C]
  u16* wKw = (u16*)(ws + 2097152);      //  2,097,152  [H][D][C]
  u16* wMw = (u16*)(ws + 4194304);      //  8,388,608  [C][H*C]
  u16* wKC = (u16*)(ws + 12582912);     // 20,971,520  smat [S][B][512][C]
  u16* wK  = (u16*)(ws + 33554432);     // 20,971,520  k [H][S][B][512][D]
  u16* wQ  = (u16*)(ws + 54525952);     // 33,554,432  q [H][B][LQ][D]
  u16* wVt = (u16*)(ws + 88080384);     // 18,350,080  Vt [S][B][C][448] (per h)
  u16* wXb = (u16*)(ws + 106430464);    // 33,554,432  Xb [B][LQ][C] (dead after q-proj)
  u16* wATs = (u16*)(ws + 106430464);   // 73,400,320  attn [S][B][LQ][448] (per h; aliases Xb)

  const int BIG = 1 << 30;

  k_cvt<<<1024, 256, 0, stream>>>(Qw, wQw, 262144);
  k_cvt<<<1024, 256, 0, stream>>>(Kw, wKw, 262144);
  k_cvt<<<4096, 256, 0, stream>>>(Mw, wMw, 1048576);
  k_transpose_x<<<dim3(128, 32, 4), 256, 0, stream>>>(base, wXb);
  k_build_smat<<<dim3(16, 32, 20), 256, 0, stream>>>(sup, wKC);

  // k-proj: k[h][s][b] = smat[s][b] @ Kw[h]^T + Kb   (M=512, N=256, K=1024)
  k8<0,false,false,true><<<dim3(2, 80), 512, 0, stream>>>(
      wKC, wKw, wK, Kb, nullptr, nullptr,
      2, C_, C_, D_, 16, 16, 0, 0,
      20, 0, (int64_t)LKM*C_, (int64_t)D_*C_, 0,
      (int64_t)S_*B_*LKM*D_, (int64_t)LKM*D_, D_, 1.f, BIG);

  // q-proj: q[h][b] = (Xb[b] @ Qw[h]^T + Qb)/16      (M=4096, N=256, K=1024)
  k8<0,false,false,true><<<dim3(16, 16), 512, 0, stream>>>(
      wXb, wQw, wQ, Qb, nullptr, nullptr,
      16, C_, C_, D_, 16, 16, 0, 0,
      4, 0, (int64_t)LQ*C_, (int64_t)D_*C_, 0,
      (int64_t)B_*LQ*D_, (int64_t)LQ*D_, D_, 1.f/16.f, BIG);

  for (int h = 0; h < H_; ++h){
    // Vt[s][b][c][k] = sum_c' Mw[c][h*C+c'] * smat[s][b][k][c']  (M=1024, N=512->448, K=1024)
    k8<0,false,false,false><<<dim3(8, 20), 512, 0, stream>>>(
        wMw + (size_t)h*C_, wKC, wVt, nullptr, nullptr, nullptr,
        4, (int64_t)H_*C_, C_, LKP, 16, 16, 0, 0,
        4, 0, 0, (int64_t)B_*LKM*C_, (int64_t)LKM*C_,
        (int64_t)B_*C_*LKP, (int64_t)C_*LKP, 0, 1.f, LKP);

    // scores+softmax for all s of this h
    k_scores<<<dim3(64, 4, 5), 256, 0, stream>>>(wQ, wK, wATs, h);

    // attAcc[b][c][l] (+)= sum_s attn[s][b][l][:] . Vt[s][b][c][:]  (M=4096(l), N=1024(c), K=5*448)
    if (h == 0){
      k8<1,true,false,false><<<dim3(64, 4), 512, 0, stream>>>(
          wATs, wVt, out, nullptr, base, Mb,
          16, LKP, LKP, LQ, 7, 35, (int64_t)B_*LQ*LKP, (int64_t)B_*C_*LKP,
          1, (int64_t)LQ*LKP, 0, (int64_t)C_*LKP, 0,
          (int64_t)C_*LQ, 0, 0, 1.f, BIG);
    } else if (h < 3){
      k8<1,false,false,false><<<dim3(64, 4), 512, 0, stream>>>(
          wATs, wVt, out, nullptr, base, Mb,
          16, LKP, LKP, LQ, 7, 35, (int64_t)B_*LQ*LKP, (int64_t)B_*C_*LKP,
          1, (int64_t)LQ*LKP, 0, (int64_t)C_*LKP, 0,
          (int64_t)C_*LQ, 0, 0, 1.f, BIG);
    } else {
      // h==3: fold final elementwise (out = base * relu(0.2*sum + Mb)) into epilogue
      k8<1,false,true,false><<<dim3(64, 4), 512, 0, stream>>>(
          wATs, wVt, out, nullptr, base, Mb,
          16, LKP, LKP, LQ, 7, 35, (int64_t)B_*LQ*LKP, (int64_t)B_*C_*LKP,
          1, (int64_t)LQ*LKP, 0, (int64_t)C_*LKP, 0,
          (int64_t)C_*LQ, 0, 0, 1.f, BIG);
    }
  }
}

// Round 5
// 799.895 us; speedup vs baseline: 1.6772x; 1.0289x over previous
//
#include <hip/hip_runtime.h>
#include <stdint.h>

#define DEVI __device__ __forceinline__

typedef __attribute__((ext_vector_type(8))) short bf16x8;
typedef __attribute__((ext_vector_type(4))) float f32x4;
typedef __attribute__((ext_vector_type(4))) unsigned short us4;
typedef unsigned short u16;

constexpr int B_ = 4, S_ = 5, H_ = 4, C_ = 1024, D_ = 256;
constexpr int LQ = 4096, LK = 400, LKP = 448, LKM = 512;

DEVI u16 f2b(float f){
  uint32_t x = __float_as_uint(f);
  uint32_t r = (x + 0x7FFFu + ((x >> 16) & 1u)) >> 16;
  return (u16)r;
}

typedef __attribute__((address_space(1))) const void ASG;
typedef __attribute__((address_space(3))) void ASL;
DEVI void gload16(const void* g, void* l){
  __builtin_amdgcn_global_load_lds((ASG*)g, (ASL*)l, 16, 0, 0);
}

// ---------------- fp32 -> bf16 convert ----------------
__global__ __launch_bounds__(256) void k_cvt(const float* __restrict__ s, u16* __restrict__ d, int n4){
  int i = blockIdx.x*256 + threadIdx.x;
  if (i >= n4) return;
  float4 v = ((const float4*)s)[i];
  us4 o; o.x = f2b(v.x); o.y = f2b(v.y); o.z = f2b(v.z); o.w = f2b(v.w);
  *(us4*)(d + (size_t)i*4) = o;
}

// ---------------- base_feat [B][C][LQ] -> Xb bf16 [B][LQ][C] ----------------
__global__ __launch_bounds__(256) void k_transpose_x(const float* __restrict__ base, u16* __restrict__ Xb){
  __shared__ float t[32][33];
  int l0 = blockIdx.x*32, c0 = blockIdx.y*32, b = blockIdx.z;
  int tx = threadIdx.x & 31, ty = threadIdx.x >> 5;
  const float* src = base + ((size_t)b*C_ + c0)*LQ + l0;
  #pragma unroll
  for (int i=0;i<4;i++){ int cc = ty + i*8; t[cc][tx] = src[(size_t)cc*LQ + tx]; }
  __syncthreads();
  u16* dst = Xb + ((size_t)b*LQ + l0)*C_ + c0;
  #pragma unroll
  for (int i=0;i<4;i++){ int ll = ty + i*8; dst[(size_t)ll*C_ + tx] = f2b(t[tx][ll]); }
}

// ---------------- support + pe -> smat_kc [S][B][512][C] (rows 400..511 zero) ----------------
__global__ __launch_bounds__(256) void k_build_smat(const float* __restrict__ sup, u16* __restrict__ kc){
  __shared__ float t[32][33];
  int p0 = blockIdx.x*32, c0 = blockIdx.y*32;
  int s = blockIdx.z / B_, b = blockIdx.z % B_;
  int tx = threadIdx.x & 31, ty = threadIdx.x >> 5;
  const float* src = sup + ((size_t)(b*S_ + s)*C_ + c0)*LK + p0;
  #pragma unroll
  for (int i=0;i<4;i++){
    int cc = ty + i*8;
    int p = p0 + tx;
    int c = c0 + cc;
    float v = 0.f;
    if (p < LK){
      v = src[(size_t)cc*LK + tx];
      float dv = expf(-(float)(c & ~1) * (9.210340371976184f / 1024.f));
      float arg = (float)p * dv;
      v += (c & 1) ? cosf(arg) : sinf(arg);
    }
    t[cc][tx] = v;
  }
  __syncthreads();
  u16* dkc = kc + ((size_t)((s*B_ + b)*LKM + p0))*C_ + c0;
  #pragma unroll
  for (int i=0;i<4;i++){ int pp = ty + i*8; dkc[(size_t)pp*C_ + tx] = f2b(t[tx][pp]); }
}

// ================= counted-vmcnt double-buffered 256x256 bf16 MFMA GEMM =================
// C[M][N] = sum_ch A_ch[M][K] * B_ch[N][K]^T   (512 threads, 8 waves 2Mx4N)
// BK=64, all 8 half-tile loads of tile t+1 issued at top of iter t; vmcnt(8)
// waits only tile t's loads (issued one full iteration ago -> latency hidden).
DEVI void stage_half(const u16* P, int64_t ld, u16* dst, int wid, int r8, int s8){
  #pragma unroll
  for (int it=0; it<2; ++it){
    int ck = wid + it*8;                              // 16 chunks of 8 rows
    gload16(P + (size_t)(ck*8 + r8)*ld + s8*8, dst + ck*512);
  }
}
DEVI bf16x8 ldsread(const u16* base, int row, int kk, int lane){
  int sl = ((kk<<2) + (lane>>4)) ^ (row & 7);
  return *(const bf16x8*)&base[row*64 + sl*8];
}

template<int CEPI, bool FIRST, bool FINAL, bool BIAS>
__global__ __launch_bounds__(512,1) void k8(
    const u16* __restrict__ A, const u16* __restrict__ Bm, void* __restrict__ Cm,
    const float* __restrict__ bias, const float* __restrict__ basep, const float* __restrict__ Mb,
    int tilesM, int64_t lda, int64_t ldb, int64_t ldc,
    int spc, int NT, int64_t aChunk, int64_t bChunk,
    int bdiv, int64_t aS0, int64_t aS1, int64_t bS0, int64_t bS1,
    int64_t cS0, int64_t cS1, int biasS0, float scale, int Nmax, int swz){
  __shared__ __align__(16) u16 lds[2][2][16384];      // [dbuf][A|B][256*64]
  int tid = threadIdx.x, lane = tid & 63, wid = tid >> 6;
  int bx = blockIdx.x;
  if (swz) bx = (bx & 7) * (gridDim.x >> 3) + (bx >> 3);   // XCD-contiguous (gx%8==0)
  int mt = bx % tilesM, ntile = bx / tilesM;
  int z = blockIdx.y, i0 = z / bdiv, i1 = z % bdiv;
  const u16* Ab = A + i0*aS0 + i1*aS1 + (size_t)mt*256*lda;
  const u16* Bb = Bm + i0*bS0 + i1*bS1 + (size_t)ntile*256*ldb;
  int r8 = lane >> 3, s8 = (lane & 7) ^ r8;
  int wr = wid >> 2, wc = wid & 3;                    // wave = (wr 0..1) x (wc 0..3)

  f32x4 acc[8][4];
  #pragma unroll
  for (int i=0;i<8;i++)
    #pragma unroll
    for (int j=0;j<4;j++) acc[i][j] = (f32x4){0.f,0.f,0.f,0.f};

  // prologue: stage K-tile 0 into buf 0
  const u16 *ApS = Ab, *BpS = Bb; int cs = 0;
  stage_half(ApS,                   lda, &lds[0][0][0],    wid, r8, s8);
  stage_half(ApS + (size_t)128*lda, lda, &lds[0][0][8192], wid, r8, s8);
  stage_half(BpS,                   ldb, &lds[0][1][0],    wid, r8, s8);
  stage_half(BpS + (size_t)128*ldb, ldb, &lds[0][1][8192], wid, r8, s8);
  ApS += 64; BpS += 64;
  if (++cs == spc){ cs = 0; ApS += aChunk - (int64_t)spc*64; BpS += bChunk - (int64_t)spc*64; }

  for (int t = 0; t < NT; ++t){
    int cur = t & 1, nxt = cur ^ 1;
    bool pf = (t + 1 < NT);
    const u16* lA = &lds[cur][0][0];
    const u16* lB = &lds[cur][1][0];
    if (pf){
      u16* sA = &lds[nxt][0][0];
      u16* sB = &lds[nxt][1][0];
      stage_half(ApS,                   lda, sA,        wid, r8, s8);
      stage_half(ApS + (size_t)128*lda, lda, sA + 8192, wid, r8, s8);
      stage_half(BpS,                   ldb, sB,        wid, r8, s8);
      stage_half(BpS + (size_t)128*ldb, ldb, sB + 8192, wid, r8, s8);
      ApS += 64; BpS += 64;
      if (++cs == spc){ cs = 0; ApS += aChunk - (int64_t)spc*64; BpS += bChunk - (int64_t)spc*64; }
      asm volatile("s_waitcnt vmcnt(8)" ::: "memory");   // tile t complete; tile t+1 in flight
    } else {
      asm volatile("s_waitcnt vmcnt(0)" ::: "memory");
    }
    asm volatile("s_barrier" ::: "memory");

    bf16x8 bfr[4][2];
    #pragma unroll
    for (int jn=0;jn<4;jn++)
      #pragma unroll
      for (int kk=0;kk<2;kk++)
        bfr[jn][kk] = ldsread(lB, wc*64 + jn*16 + (lane & 15), kk, lane);

    #pragma unroll
    for (int p = 0; p < 4; ++p){
      bf16x8 af[2][2];
      #pragma unroll
      for (int dm=0;dm<2;dm++)
        #pragma unroll
        for (int kk=0;kk<2;kk++)
          af[dm][kk] = ldsread(lA, wr*128 + (p*2+dm)*16 + (lane & 15), kk, lane);
      __builtin_amdgcn_s_setprio(1);
      #pragma unroll
      for (int dm=0;dm<2;dm++)
        #pragma unroll
        for (int jn=0;jn<4;jn++)
          #pragma unroll
          for (int kk=0;kk<2;kk++)
            acc[p*2+dm][jn] = __builtin_amdgcn_mfma_f32_16x16x32_bf16(af[dm][kk], bfr[jn][kk], acc[p*2+dm][jn], 0,0,0);
      __builtin_amdgcn_s_setprio(0);
    }
    asm volatile("s_barrier" ::: "memory");   // all reads of buf[cur] done before next stages
  }

  int g = lane >> 4, c16 = lane & 15;
  if constexpr (CEPI == 0){
    u16* Cb = (u16*)Cm + i0*cS0 + i1*cS1;
    #pragma unroll
    for (int jn=0;jn<4;jn++){
      int n = ntile*256 + wc*64 + jn*16 + c16;
      if (n >= Nmax) continue;
      float bv = 0.f;
      if (BIAS) bv = bias[(size_t)i0*biasS0 + n];
      #pragma unroll
      for (int im=0;im<8;im++){
        int m = mt*256 + wr*128 + im*16 + g*4;
        #pragma unroll
        for (int r=0;r<4;r++)
          Cb[(size_t)(m + r)*ldc + n] = f2b((acc[im][jn][r] + bv)*scale);
      }
    }
  } else {
    float* Cb = (float*)Cm + i0*cS0 + i1*cS1;
    const float* Bs = basep + i0*cS0 + i1*cS1;
    #pragma unroll
    for (int jn=0;jn<4;jn++){
      int n = ntile*256 + wc*64 + jn*16 + c16;
      float mbv = 0.f;
      if (FINAL) mbv = Mb[n];
      #pragma unroll
      for (int im=0;im<8;im++){
        int m = mt*256 + wr*128 + im*16 + g*4;
        float* p = Cb + (size_t)n*ldc + m;
        float4 v;
        v.x = acc[im][jn][0]; v.y = acc[im][jn][1]; v.z = acc[im][jn][2]; v.w = acc[im][jn][3];
        if (!FIRST){
          float4 old = *(const float4*)p;
          v.x += old.x; v.y += old.y; v.z += old.z; v.w += old.w;
        }
        if (FINAL){
          float4 bs = *(const float4*)(Bs + (size_t)n*ldc + m);
          v.x = bs.x * fmaxf(0.2f*v.x + mbv, 0.f);
          v.y = bs.y * fmaxf(0.2f*v.y + mbv, 0.f);
          v.z = bs.z * fmaxf(0.2f*v.z + mbv, 0.f);
          v.w = bs.w * fmaxf(0.2f*v.w + mbv, 0.f);
        }
        *(float4*)p = v;
      }
    }
  }
}

// ---------------- fused QK^T + softmax -> attn bf16 [S][B][LQ][448] (per h, all s) ----------------
// 128 q-rows per block, 8 waves (16 rows each), K panel staged once per 128 rows.
__global__ __launch_bounds__(512) void k_scores(
    const u16* __restrict__ qws, const u16* __restrict__ kws,
    u16* __restrict__ attn, int h){
  __shared__ __align__(16) u16 lQ[128*64];
  __shared__ __align__(16) u16 lK[400*64];
  int tid = threadIdx.x, lane = tid & 63, wid = tid >> 6;
  int m0 = blockIdx.x * 128;
  int b = blockIdx.y;
  int s = blockIdx.z;
  const u16* Qp = qws + ((size_t)(h*B_ + b)*LQ + m0)*D_;
  const u16* Kp = kws + ((size_t)((h*S_ + s)*B_ + b))*((size_t)LKM*D_);
  int r8 = lane >> 3, s8 = (lane & 7) ^ r8;
  f32x4 acc[25];
  #pragma unroll
  for (int t=0;t<25;t++) acc[t] = (f32x4){0.f,0.f,0.f,0.f};
  int wm = wid * 16;
  for (int k0 = 0; k0 < 256; k0 += 64){
    __syncthreads();
    #pragma unroll
    for (int c = 0; c < 2; ++c){
      int cc = wid + c*8;                       // 16 Q chunks
      int row = cc*8 + r8;
      gload16(Qp + (size_t)row*D_ + k0 + s8*8, &lQ[cc*512]);
    }
    for (int cc = wid; cc < 50; cc += 8){       // 50 K chunks
      int row = cc*8 + r8;
      gload16(Kp + (size_t)row*D_ + k0 + s8*8, &lK[cc*512]);
    }
    __syncthreads();
    #pragma unroll
    for (int kk = 0; kk < 2; ++kk){
      int rowA = wm + (lane & 15);
      int slA = ((kk<<2) + (lane>>4)) ^ (rowA & 7);
      bf16x8 af = *(const bf16x8*)&lQ[rowA*64 + slA*8];
      #pragma unroll
      for (int t=0;t<25;t++){
        int rowB = t*16 + (lane & 15);
        int slB = ((kk<<2) + (lane>>4)) ^ (rowB & 7);
        bf16x8 bf = *(const bf16x8*)&lK[rowB*64 + slB*8];
        acc[t] = __builtin_amdgcn_mfma_f32_16x16x32_bf16(af, bf, acc[t], 0,0,0);
      }
    }
  }
  float mx[4] = {-1e30f,-1e30f,-1e30f,-1e30f};
  #pragma unroll
  for (int t=0;t<25;t++)
    #pragma unroll
    for (int r=0;r<4;r++) mx[r] = fmaxf(mx[r], acc[t][r]);
  #pragma unroll
  for (int r=0;r<4;r++){
    mx[r] = fmaxf(mx[r], __shfl_xor(mx[r], 1));
    mx[r] = fmaxf(mx[r], __shfl_xor(mx[r], 2));
    mx[r] = fmaxf(mx[r], __shfl_xor(mx[r], 4));
    mx[r] = fmaxf(mx[r], __shfl_xor(mx[r], 8));
  }
  float sm[4] = {0.f,0.f,0.f,0.f};
  #pragma unroll
  for (int t=0;t<25;t++)
    #pragma unroll
    for (int r=0;r<4;r++){ float e = __expf(acc[t][r] - mx[r]); acc[t][r] = e; sm[r] += e; }
  #pragma unroll
  for (int r=0;r<4;r++){
    sm[r] += __shfl_xor(sm[r], 1);
    sm[r] += __shfl_xor(sm[r], 2);
    sm[r] += __shfl_xor(sm[r], 4);
    sm[r] += __shfl_xor(sm[r], 8);
    sm[r] = 1.f / sm[r];
  }
  u16* ap = attn + ((size_t)((s*B_ + b)*LQ) + m0 + wm)*LKP;
  int g = lane >> 4, c16 = lane & 15;
  #pragma unroll
  for (int t=0;t<25;t++)
    #pragma unroll
    for (int r=0;r<4;r++)
      ap[(size_t)(g*4 + r)*LKP + t*16 + c16] = f2b(acc[t][r] * sm[r]);
  for (int t = lane; t < 16*48; t += 64){
    int rr = t / 48, cp = 400 + (t % 48);
    ap[(size_t)rr*LKP + cp] = 0;
  }
}

extern "C" void kernel_launch(void* const* d_in, const int* in_sizes, int n_in,
                              void* d_out, int out_size, void* d_ws, size_t ws_size,
                              hipStream_t stream){
  const float* base = (const float*)d_in[0];
  const float* sup  = (const float*)d_in[1];
  const float* Qw   = (const float*)d_in[2];
  const float* Qb   = (const float*)d_in[3];
  const float* Kw   = (const float*)d_in[4];
  const float* Kb   = (const float*)d_in[5];
  const float* Mw   = (const float*)d_in[6];
  const float* Mb   = (const float*)d_in[7];
  float* out = (float*)d_out;
  char* ws = (char*)d_ws;

  // workspace layout (bytes) — total 179,830,784 (~171.5 MiB)
  u16* wQw = (u16*)(ws + 0);            //  2,097,152  [H][D][C]
  u16* wKw = (u16*)(ws + 2097152);      //  2,097,152  [H][D][C]
  u16* wMw = (u16*)(ws + 4194304);      //  8,388,608  [C][H*C]
  u16* wKC = (u16*)(ws + 12582912);     // 20,971,520  smat [S][B][512][C]
  u16* wK  = (u16*)(ws + 33554432);     // 20,971,520  k [H][S][B][512][D]
  u16* wQ  = (u16*)(ws + 54525952);     // 33,554,432  q [H][B][LQ][D]
  u16* wVt = (u16*)(ws + 88080384);     // 18,350,080  Vt [S][B][C][448] (per h)
  u16* wXb = (u16*)(ws + 106430464);    // 33,554,432  Xb [B][LQ][C] (dead after q-proj)
  u16* wATs = (u16*)(ws + 106430464);   // 73,400,320  attn [S][B][LQ][448] (per h; aliases Xb)

  const int BIG = 1 << 30;

  k_cvt<<<1024, 256, 0, stream>>>(Qw, wQw, 262144);
  k_cvt<<<1024, 256, 0, stream>>>(Kw, wKw, 262144);
  k_cvt<<<4096, 256, 0, stream>>>(Mw, wMw, 1048576);
  k_transpose_x<<<dim3(128, 32, 4), 256, 0, stream>>>(base, wXb);
  k_build_smat<<<dim3(16, 32, 20), 256, 0, stream>>>(sup, wKC);

  // k-proj: k[h][s][b] = smat[s][b] @ Kw[h]^T + Kb   (M=512, N=256, K=1024)
  k8<0,false,false,true><<<dim3(2, 80), 512, 0, stream>>>(
      wKC, wKw, wK, Kb, nullptr, nullptr,
      2, C_, C_, D_, 16, 16, 0, 0,
      20, 0, (int64_t)LKM*C_, (int64_t)D_*C_, 0,
      (int64_t)S_*B_*LKM*D_, (int64_t)LKM*D_, D_, 1.f, BIG, 0);

  // q-proj: q[h][b] = (Xb[b] @ Qw[h]^T + Qb)/16      (M=4096, N=256, K=1024)
  k8<0,false,false,true><<<dim3(16, 16), 512, 0, stream>>>(
      wXb, wQw, wQ, Qb, nullptr, nullptr,
      16, C_, C_, D_, 16, 16, 0, 0,
      4, 0, (int64_t)LQ*C_, (int64_t)D_*C_, 0,
      (int64_t)B_*LQ*D_, (int64_t)LQ*D_, D_, 1.f/16.f, BIG, 1);

  for (int h = 0; h < H_; ++h){
    // Vt[s][b][c][k] = sum_c' Mw[c][h*C+c'] * smat[s][b][k][c']  (M=1024, N=512->448, K=1024)
    k8<0,false,false,false><<<dim3(8, 20), 512, 0, stream>>>(
        wMw + (size_t)h*C_, wKC, wVt, nullptr, nullptr, nullptr,
        4, (int64_t)H_*C_, C_, LKP, 16, 16, 0, 0,
        4, 0, 0, (int64_t)B_*LKM*C_, (int64_t)LKM*C_,
        (int64_t)B_*C_*LKP, (int64_t)C_*LKP, 0, 1.f, LKP, 0);

    // scores+softmax for all s of this h (128 rows/block, 8 waves)
    k_scores<<<dim3(32, 4, 5), 512, 0, stream>>>(wQ, wK, wATs, h);

    // attAcc[b][c][l] (+)= sum_s attn[s][b][l][:] . Vt[s][b][c][:]  (M=4096(l), N=1024(c), K=5*448)
    if (h == 0){
      k8<1,true,false,false><<<dim3(64, 4), 512, 0, stream>>>(
          wATs, wVt, out, nullptr, base, Mb,
          16, LKP, LKP, LQ, 7, 35, (int64_t)B_*LQ*LKP, (int64_t)B_*C_*LKP,
          1, (int64_t)LQ*LKP, 0, (int64_t)C_*LKP, 0,
          (int64_t)C_*LQ, 0, 0, 1.f, BIG, 1);
    } else if (h < 3){
      k8<1,false,false,false><<<dim3(64, 4), 512, 0, stream>>>(
          wATs, wVt, out, nullptr, base, Mb,
          16, LKP, LKP, LQ, 7, 35, (int64_t)B_*LQ*LKP, (int64_t)B_*C_*LKP,
          1, (int64_t)LQ*LKP, 0, (int64_t)C_*LKP, 0,
          (int64_t)C_*LQ, 0, 0, 1.f, BIG, 1);
    } else {
      // h==3: fold final elementwise (out = base * relu(0.2*sum + Mb)) into epilogue
      k8<1,false,true,false><<<dim3(64, 4), 512, 0, stream>>>(
          wATs, wVt, out, nullptr, base, Mb,
          16, LKP, LKP, LQ, 7, 35, (int64_t)B_*LQ*LKP, (int64_t)B_*C_*LKP,
          1, (int64_t)LQ*LKP, 0, (int64_t)C_*LKP, 0,
          (int64_t)C_*LQ, 0, 0, 1.f, BIG, 1);
    }
  }
}

// Round 6
// 758.924 us; speedup vs baseline: 1.7678x; 1.0540x over previous
//
#include <hip/hip_runtime.h>
#include <stdint.h>

#define DEVI __device__ __forceinline__

typedef __attribute__((ext_vector_type(8))) short bf16x8;
typedef __attribute__((ext_vector_type(4))) float f32x4;
typedef __attribute__((ext_vector_type(4))) unsigned short us4;
typedef unsigned short u16;

constexpr int B_ = 4, S_ = 5, H_ = 4, C_ = 1024, D_ = 256;
constexpr int LQ = 4096, LK = 400, LKP = 448;

DEVI u16 f2b(float f){
  uint32_t x = __float_as_uint(f);
  uint32_t r = (x + 0x7FFFu + ((x >> 16) & 1u)) >> 16;
  return (u16)r;
}

typedef __attribute__((address_space(1))) const void ASG;
typedef __attribute__((address_space(3))) void ASL;
DEVI void gload16(const void* g, void* l){
  __builtin_amdgcn_global_load_lds((ASG*)g, (ASL*)l, 16, 0, 0);
}

// ---------------- fp32 -> bf16 convert ----------------
__global__ __launch_bounds__(256) void k_cvt(const float* __restrict__ s, u16* __restrict__ d, int n4){
  int i = blockIdx.x*256 + threadIdx.x;
  if (i >= n4) return;
  float4 v = ((const float4*)s)[i];
  us4 o; o.x = f2b(v.x); o.y = f2b(v.y); o.z = f2b(v.z); o.w = f2b(v.w);
  *(us4*)(d + (size_t)i*4) = o;
}

// ---------------- base_feat [B][C][LQ] -> Xb bf16 [B][LQ][C] ----------------
__global__ __launch_bounds__(256) void k_transpose_x(const float* __restrict__ base, u16* __restrict__ Xb){
  __shared__ float t[32][33];
  int l0 = blockIdx.x*32, c0 = blockIdx.y*32, b = blockIdx.z;
  int tx = threadIdx.x & 31, ty = threadIdx.x >> 5;
  const float* src = base + ((size_t)b*C_ + c0)*LQ + l0;
  #pragma unroll
  for (int i=0;i<4;i++){ int cc = ty + i*8; t[cc][tx] = src[(size_t)cc*LQ + tx]; }
  __syncthreads();
  u16* dst = Xb + ((size_t)b*LQ + l0)*C_ + c0;
  #pragma unroll
  for (int i=0;i<4;i++){ int ll = ty + i*8; dst[(size_t)ll*C_ + tx] = f2b(t[tx][ll]); }
}

// ---------------- support + pe -> smat [S][B][448][C] (rows 400..447 zero) ----------------
__global__ __launch_bounds__(256) void k_build_smat(const float* __restrict__ sup, u16* __restrict__ kc){
  __shared__ float t[32][33];
  int p0 = blockIdx.x*32, c0 = blockIdx.y*32;
  int s = blockIdx.z / B_, b = blockIdx.z % B_;
  int tx = threadIdx.x & 31, ty = threadIdx.x >> 5;
  const float* src = sup + ((size_t)(b*S_ + s)*C_ + c0)*LK + p0;
  #pragma unroll
  for (int i=0;i<4;i++){
    int cc = ty + i*8;
    int p = p0 + tx;
    int c = c0 + cc;
    float v = 0.f;
    if (p < LK){
      v = src[(size_t)cc*LK + tx];
      float dv = expf(-(float)(c & ~1) * (9.210340371976184f / 1024.f));
      float arg = (float)p * dv;
      v += (c & 1) ? cosf(arg) : sinf(arg);
    }
    t[cc][tx] = v;
  }
  __syncthreads();
  u16* dkc = kc + ((size_t)((s*B_ + b)*LKP + p0))*C_ + c0;
  #pragma unroll
  for (int i=0;i<4;i++){ int pp = ty + i*8; dkc[(size_t)pp*C_ + tx] = f2b(t[tx][pp]); }
}

// ================= counted-vmcnt double-buffered 256x256 bf16 MFMA GEMM =================
// C[M][N] = sum_ch A_ch[M][K] * B_ch[N][K]^T   (512 threads, 8 waves 2Mx4N)
// BK=64; all 8 half-tile loads of tile t+1 issued at top of iter t; vmcnt(8).
// swz: 0 none; 1 generic XCD-contig (gx%8==0); 2 PV-specific (grid.x==64):
//      mt=2*xcd+(j>>2), nt=j&3 -> all nt of an mt-pair on ONE XCD (L2 reuse).
DEVI void stage_half(const u16* P, int64_t ld, u16* dst, int wid, int r8, int s8){
  #pragma unroll
  for (int it=0; it<2; ++it){
    int ck = wid + it*8;                              // 16 chunks of 8 rows
    gload16(P + (size_t)(ck*8 + r8)*ld + s8*8, dst + ck*512);
  }
}
DEVI bf16x8 ldsread(const u16* base, int row, int kk, int lane){
  int sl = ((kk<<2) + (lane>>4)) ^ (row & 7);
  return *(const bf16x8*)&base[row*64 + sl*8];
}

template<int CEPI, bool FIRST, bool FINAL, bool BIAS>
__global__ __launch_bounds__(512,1) void k8(
    const u16* __restrict__ A, const u16* __restrict__ Bm, void* __restrict__ Cm,
    const float* __restrict__ bias, const float* __restrict__ basep, const float* __restrict__ Mb,
    int tilesM, int64_t lda, int64_t ldb, int64_t ldc,
    int spc, int NT, int64_t aChunk, int64_t bChunk,
    int bdiv, int64_t aS0, int64_t aS1, int64_t bS0, int64_t bS1,
    int64_t cS0, int64_t cS1, int biasS0, float scale, int Nmax, int Mmax, int swz){
  __shared__ __align__(16) u16 lds[2][2][16384];      // [dbuf][A|B][256*64]
  int tid = threadIdx.x, lane = tid & 63, wid = tid >> 6;
  int bx = blockIdx.x;
  int mt, ntile;
  if (swz == 2){ int x = bx & 7, j = bx >> 3; mt = 2*x + (j >> 2); ntile = j & 3; }
  else {
    if (swz == 1) bx = (bx & 7) * (gridDim.x >> 3) + (bx >> 3);
    mt = bx % tilesM; ntile = bx / tilesM;
  }
  int z = blockIdx.y, i0 = z / bdiv, i1 = z % bdiv;
  const u16* Ab = A + i0*aS0 + i1*aS1 + (size_t)mt*256*lda;
  const u16* Bb = Bm + i0*bS0 + i1*bS1 + (size_t)ntile*256*ldb;
  int r8 = lane >> 3, s8 = (lane & 7) ^ r8;
  int wr = wid >> 2, wc = wid & 3;                    // wave = (wr 0..1) x (wc 0..3)

  f32x4 acc[8][4];
  #pragma unroll
  for (int i=0;i<8;i++)
    #pragma unroll
    for (int j=0;j<4;j++) acc[i][j] = (f32x4){0.f,0.f,0.f,0.f};

  // prologue: stage K-tile 0 into buf 0
  const u16 *ApS = Ab, *BpS = Bb; int cs = 0;
  stage_half(ApS,                   lda, &lds[0][0][0],    wid, r8, s8);
  stage_half(ApS + (size_t)128*lda, lda, &lds[0][0][8192], wid, r8, s8);
  stage_half(BpS,                   ldb, &lds[0][1][0],    wid, r8, s8);
  stage_half(BpS + (size_t)128*ldb, ldb, &lds[0][1][8192], wid, r8, s8);
  ApS += 64; BpS += 64;
  if (++cs == spc){ cs = 0; ApS += aChunk - (int64_t)spc*64; BpS += bChunk - (int64_t)spc*64; }

  for (int t = 0; t < NT; ++t){
    int cur = t & 1, nxt = cur ^ 1;
    bool pf = (t + 1 < NT);
    const u16* lA = &lds[cur][0][0];
    const u16* lB = &lds[cur][1][0];
    if (pf){
      u16* sA = &lds[nxt][0][0];
      u16* sB = &lds[nxt][1][0];
      stage_half(ApS,                   lda, sA,        wid, r8, s8);
      stage_half(ApS + (size_t)128*lda, lda, sA + 8192, wid, r8, s8);
      stage_half(BpS,                   ldb, sB,        wid, r8, s8);
      stage_half(BpS + (size_t)128*ldb, ldb, sB + 8192, wid, r8, s8);
      ApS += 64; BpS += 64;
      if (++cs == spc){ cs = 0; ApS += aChunk - (int64_t)spc*64; BpS += bChunk - (int64_t)spc*64; }
      asm volatile("s_waitcnt vmcnt(8)" ::: "memory");   // tile t complete; t+1 in flight
    } else {
      asm volatile("s_waitcnt vmcnt(0)" ::: "memory");
    }
    asm volatile("s_barrier" ::: "memory");

    bf16x8 bfr[4][2];
    #pragma unroll
    for (int jn=0;jn<4;jn++)
      #pragma unroll
      for (int kk=0;kk<2;kk++)
        bfr[jn][kk] = ldsread(lB, wc*64 + jn*16 + (lane & 15), kk, lane);

    #pragma unroll
    for (int p = 0; p < 4; ++p){
      bf16x8 af[2][2];
      #pragma unroll
      for (int dm=0;dm<2;dm++)
        #pragma unroll
        for (int kk=0;kk<2;kk++)
          af[dm][kk] = ldsread(lA, wr*128 + (p*2+dm)*16 + (lane & 15), kk, lane);
      __builtin_amdgcn_s_setprio(1);
      #pragma unroll
      for (int dm=0;dm<2;dm++)
        #pragma unroll
        for (int jn=0;jn<4;jn++)
          #pragma unroll
          for (int kk=0;kk<2;kk++)
            acc[p*2+dm][jn] = __builtin_amdgcn_mfma_f32_16x16x32_bf16(af[dm][kk], bfr[jn][kk], acc[p*2+dm][jn], 0,0,0);
      __builtin_amdgcn_s_setprio(0);
    }
    asm volatile("s_barrier" ::: "memory");   // all reads of buf[cur] done before next stages
  }

  int g = lane >> 4, c16 = lane & 15;
  if constexpr (CEPI == 0){
    u16* Cb = (u16*)Cm + i0*cS0 + i1*cS1;
    #pragma unroll
    for (int jn=0;jn<4;jn++){
      int n = ntile*256 + wc*64 + jn*16 + c16;
      if (n >= Nmax) continue;
      float bv = 0.f;
      if (BIAS) bv = bias[(size_t)i0*biasS0 + n];
      #pragma unroll
      for (int im=0;im<8;im++){
        int m = mt*256 + wr*128 + im*16 + g*4;
        if (m >= Mmax) continue;
        #pragma unroll
        for (int r=0;r<4;r++)
          Cb[(size_t)(m + r)*ldc + n] = f2b((acc[im][jn][r] + bv)*scale);
      }
    }
  } else {
    float* Cb = (float*)Cm + i0*cS0 + i1*cS1;
    const float* Bs = basep + i0*cS0 + i1*cS1;
    #pragma unroll
    for (int jn=0;jn<4;jn++){
      int n = ntile*256 + wc*64 + jn*16 + c16;
      float mbv = 0.f;
      if (FINAL) mbv = Mb[n];
      #pragma unroll
      for (int im=0;im<8;im++){
        int m = mt*256 + wr*128 + im*16 + g*4;
        float* p = Cb + (size_t)n*ldc + m;
        float4 v;
        v.x = acc[im][jn][0]; v.y = acc[im][jn][1]; v.z = acc[im][jn][2]; v.w = acc[im][jn][3];
        if (!FIRST){
          float4 old = *(const float4*)p;
          v.x += old.x; v.y += old.y; v.z += old.z; v.w += old.w;
        }
        if (FINAL){
          float4 bs = *(const float4*)(Bs + (size_t)n*ldc + m);
          v.x = bs.x * fmaxf(0.2f*v.x + mbv, 0.f);
          v.y = bs.y * fmaxf(0.2f*v.y + mbv, 0.f);
          v.z = bs.z * fmaxf(0.2f*v.z + mbv, 0.f);
          v.w = bs.w * fmaxf(0.2f*v.w + mbv, 0.f);
        }
        *(float4*)p = v;
      }
    }
  }
}

// ---------------- fused QK^T + softmax -> attn bf16 [GH*S][B][LQ][448] ----------------
// 128 q-rows per block, 8 waves (16 rows each); z = hh*5+s, h = h0+hh.
__global__ __launch_bounds__(512) void k_scores(
    const u16* __restrict__ qws, const u16* __restrict__ kws,
    u16* __restrict__ attn, int h0){
  __shared__ __align__(16) u16 lQ[128*64];
  __shared__ __align__(16) u16 lK[400*64];
  int tid = threadIdx.x, lane = tid & 63, wid = tid >> 6;
  int m0 = blockIdx.x * 128;
  int b = blockIdx.y;
  int zz = blockIdx.z;
  int s = zz % 5, h = h0 + zz / 5;
  const u16* Qp = qws + ((size_t)(h*B_ + b)*LQ + m0)*D_;
  const u16* Kp = kws + ((size_t)((h*S_ + s)*B_ + b))*((size_t)LKP*D_);
  int r8 = lane >> 3, s8 = (lane & 7) ^ r8;
  f32x4 acc[25];
  #pragma unroll
  for (int t=0;t<25;t++) acc[t] = (f32x4){0.f,0.f,0.f,0.f};
  int wm = wid * 16;
  for (int k0 = 0; k0 < 256; k0 += 64){
    __syncthreads();
    #pragma unroll
    for (int c = 0; c < 2; ++c){
      int cc = wid + c*8;                       // 16 Q chunks
      int row = cc*8 + r8;
      gload16(Qp + (size_t)row*D_ + k0 + s8*8, &lQ[cc*512]);
    }
    for (int cc = wid; cc < 50; cc += 8){       // 50 K chunks
      int row = cc*8 + r8;
      gload16(Kp + (size_t)row*D_ + k0 + s8*8, &lK[cc*512]);
    }
    __syncthreads();
    #pragma unroll
    for (int kk = 0; kk < 2; ++kk){
      int rowA = wm + (lane & 15);
      int slA = ((kk<<2) + (lane>>4)) ^ (rowA & 7);
      bf16x8 af = *(const bf16x8*)&lQ[rowA*64 + slA*8];
      #pragma unroll
      for (int t=0;t<25;t++){
        int rowB = t*16 + (lane & 15);
        int slB = ((kk<<2) + (lane>>4)) ^ (rowB & 7);
        bf16x8 bf = *(const bf16x8*)&lK[rowB*64 + slB*8];
        acc[t] = __builtin_amdgcn_mfma_f32_16x16x32_bf16(af, bf, acc[t], 0,0,0);
      }
    }
  }
  float mx[4] = {-1e30f,-1e30f,-1e30f,-1e30f};
  #pragma unroll
  for (int t=0;t<25;t++)
    #pragma unroll
    for (int r=0;r<4;r++) mx[r] = fmaxf(mx[r], acc[t][r]);
  #pragma unroll
  for (int r=0;r<4;r++){
    mx[r] = fmaxf(mx[r], __shfl_xor(mx[r], 1));
    mx[r] = fmaxf(mx[r], __shfl_xor(mx[r], 2));
    mx[r] = fmaxf(mx[r], __shfl_xor(mx[r], 4));
    mx[r] = fmaxf(mx[r], __shfl_xor(mx[r], 8));
  }
  float sm[4] = {0.f,0.f,0.f,0.f};
  #pragma unroll
  for (int t=0;t<25;t++)
    #pragma unroll
    for (int r=0;r<4;r++){ float e = __expf(acc[t][r] - mx[r]); acc[t][r] = e; sm[r] += e; }
  #pragma unroll
  for (int r=0;r<4;r++){
    sm[r] += __shfl_xor(sm[r], 1);
    sm[r] += __shfl_xor(sm[r], 2);
    sm[r] += __shfl_xor(sm[r], 4);
    sm[r] += __shfl_xor(sm[r], 8);
    sm[r] = 1.f / sm[r];
  }
  u16* ap = attn + ((size_t)((zz*B_ + b)*LQ) + m0 + wm)*LKP;
  int g = lane >> 4, c16 = lane & 15;
  #pragma unroll
  for (int t=0;t<25;t++)
    #pragma unroll
    for (int r=0;r<4;r++)
      ap[(size_t)(g*4 + r)*LKP + t*16 + c16] = f2b(acc[t][r] * sm[r]);
  for (int t = lane; t < 16*48; t += 64){
    int rr = t / 48, cp = 400 + (t % 48);
    ap[(size_t)rr*LKP + cp] = 0;
  }
}

extern "C" void kernel_launch(void* const* d_in, const int* in_sizes, int n_in,
                              void* d_out, int out_size, void* d_ws, size_t ws_size,
                              hipStream_t stream){
  const float* base = (const float*)d_in[0];
  const float* sup  = (const float*)d_in[1];
  const float* Qw   = (const float*)d_in[2];
  const float* Qb   = (const float*)d_in[3];
  const float* Kw   = (const float*)d_in[4];
  const float* Kb   = (const float*)d_in[5];
  const float* Mw   = (const float*)d_in[6];
  const float* Mb   = (const float*)d_in[7];
  float* out = (float*)d_out;
  char* ws = (char*)d_ws;

  // workspace layout (bytes):
  // GH=2: ... + Vt 36,700,160 + attn 146,800,640 -> total 266,338,304
  // GH=1: ... + Vt 18,350,080 + attn  73,400,320 -> total 174,587,904
  u16* wQw = (u16*)(ws + 0);            //  2,097,152  [H][D][C]
  u16* wKw = (u16*)(ws + 2097152);      //  2,097,152  [H][D][C]
  u16* wMw = (u16*)(ws + 4194304);      //  8,388,608  [C][H*C]
  u16* wKC = (u16*)(ws + 12582912);     // 18,350,080  smat [S*B][448][C]
  u16* wK  = (u16*)(ws + 30932992);     // 18,350,080  k [H][S][B][448][D]
  u16* wQ  = (u16*)(ws + 49283072);     // 33,554,432  q [H][B][LQ][D]
  u16* wVt = (u16*)(ws + 82837504);     // GH*18,350,080  Vt [GH*S][B][C][448]

  const int GH = (ws_size >= 266338304ull) ? 2 : 1;   // heads per group
  const int NG = H_ / GH;
  u16* wAT = (u16*)(ws + 82837504 + (size_t)GH*18350080ull);  // attn [GH*S][B][LQ][448]
  u16* wXb = wAT;                                             // Xb [B][LQ][C] (dead after q-proj)

  const int BIG = 1 << 30;

  k_cvt<<<1024, 256, 0, stream>>>(Qw, wQw, 262144);
  k_cvt<<<1024, 256, 0, stream>>>(Kw, wKw, 262144);
  k_cvt<<<4096, 256, 0, stream>>>(Mw, wMw, 1048576);
  k_transpose_x<<<dim3(128, 32, 4), 256, 0, stream>>>(base, wXb);
  k_build_smat<<<dim3(14, 32, 20), 256, 0, stream>>>(sup, wKC);

  // k-proj: k[h][s][b] = smat[s][b] @ Kw[h]^T + Kb   (M=448(512 masked), N=256, K=1024)
  k8<0,false,false,true><<<dim3(2, 80), 512, 0, stream>>>(
      wKC, wKw, wK, Kb, nullptr, nullptr,
      2, C_, C_, D_, 16, 16, 1024, 1024,
      20, 0, (int64_t)LKP*C_, (int64_t)D_*C_, 0,
      (int64_t)S_*B_*LKP*D_, (int64_t)LKP*D_, D_, 1.f, BIG, LKP, 0);

  // q-proj: q[h][b] = (Xb[b] @ Qw[h]^T + Qb)/16      (M=4096, N=256, K=1024)
  k8<0,false,false,true><<<dim3(16, 16), 512, 0, stream>>>(
      wXb, wQw, wQ, Qb, nullptr, nullptr,
      16, C_, C_, D_, 16, 16, 1024, 1024,
      4, 0, (int64_t)LQ*C_, (int64_t)D_*C_, 0,
      (int64_t)B_*LQ*D_, (int64_t)LQ*D_, D_, 1.f/16.f, BIG, BIG, 1);

  for (int g = 0; g < NG; ++g){
    // Vt[hh*S+s][b][c][k] = sum_c' Mw[c][(g*GH+hh)*C+c'] * smat[s][b][k][c']
    k8<0,false,false,false><<<dim3(8, GH*20), 512, 0, stream>>>(
        wMw + (size_t)(g*GH)*C_, wKC, wVt, nullptr, nullptr, nullptr,
        4, (int64_t)H_*C_, C_, LKP, 16, 16, 1024, 1024,
        20, (int64_t)C_, 0, 0, (int64_t)LKP*C_,
        (int64_t)20*C_*LKP, (int64_t)C_*LKP, 0, 1.f, LKP, BIG, 0);

    // scores+softmax for heads g*GH..g*GH+GH-1, all s
    k_scores<<<dim3(32, 4, GH*5), 512, 0, stream>>>(wQ, wK, wAT, g*GH);

    // attAcc[b][c][l] (+)= sum_{hh,s} attn[hh*5+s][b][l][:] . Vt[hh*5+s][b][c][:]
    // M=4096(l), N=1024(c), K=GH*5*448; swz=2 puts all nt of an mt-pair on one XCD.
    if (g == 0){
      k8<1,true,false,false><<<dim3(64, 4), 512, 0, stream>>>(
          wAT, wVt, out, nullptr, base, Mb,
          16, LKP, LKP, LQ, 7, GH*35, (int64_t)B_*LQ*LKP, (int64_t)B_*C_*LKP,
          1, (int64_t)LQ*LKP, 0, (int64_t)C_*LKP, 0,
          (int64_t)C_*LQ, 0, 0, 1.f, BIG, BIG, 2);
    } else if (g == NG - 1){
      // last group: fold final elementwise (out = base * relu(0.2*sum + Mb))
      k8<1,false,true,false><<<dim3(64, 4), 512, 0, stream>>>(
          wAT, wVt, out, nullptr, base, Mb,
          16, LKP, LKP, LQ, 7, GH*35, (int64_t)B_*LQ*LKP, (int64_t)B_*C_*LKP,
          1, (int64_t)LQ*LKP, 0, (int64_t)C_*LKP, 0,
          (int64_t)C_*LQ, 0, 0, 1.f, BIG, BIG, 2);
    } else {
      k8<1,false,false,false><<<dim3(64, 4), 512, 0, stream>>>(
          wAT, wVt, out, nullptr, base, Mb,
          16, LKP, LKP, LQ, 7, GH*35, (int64_t)B_*LQ*LKP, (int64_t)B_*C_*LKP,
          1, (int64_t)LQ*LKP, 0, (int64_t)C_*LKP, 0,
          (int64_t)C_*LQ, 0, 0, 1.f, BIG, BIG, 2);
    }
  }
}